// Round 1
// baseline (751.943 us; speedup 1.0000x reference)
//
#include <hip/hip_runtime.h>
#include <hip/hip_bf16.h>

#define N_NODES 50000
#define N_EDGES 800000
#define IN_C 128
#define HID_C 128
#define OUT_C 64

// ---------------------------------------------------------------------------
// CSR build: histogram of dst, exclusive scan -> row_ptr, fill edge_src
// ---------------------------------------------------------------------------
__global__ void degree_kernel(const int* __restrict__ dst, int E, int* __restrict__ hist) {
    int e = blockIdx.x * blockDim.x + threadIdx.x;
    if (e < E) atomicAdd(&hist[dst[e]], 1);
}

__global__ void dinv_kernel(const int* __restrict__ hist, float* __restrict__ dinv, int n) {
    int i = blockIdx.x * blockDim.x + threadIdx.x;
    if (i < n) dinv[i] = rsqrtf((float)(hist[i] + 1));  // +1 self loop
}

__global__ __launch_bounds__(1024)
void scan_kernel(const int* __restrict__ hist, int* __restrict__ row_ptr,
                 int* __restrict__ cursor, int n) {
    __shared__ int sums[1024];
    int t = threadIdx.x;
    int chunk = (n + 1023) >> 10;
    int start = t * chunk;
    int end = min(start + chunk, n);
    int s = 0;
    for (int i = start; i < end; ++i) s += hist[i];
    sums[t] = s;
    __syncthreads();
    for (int off = 1; off < 1024; off <<= 1) {
        int v = (t >= off) ? sums[t - off] : 0;
        __syncthreads();
        sums[t] += v;
        __syncthreads();
    }
    int run = sums[t] - s;  // exclusive prefix of this thread's chunk
    for (int i = start; i < end; ++i) {
        row_ptr[i] = run;
        cursor[i]  = run;
        run += hist[i];
    }
    if (t == 1023) row_ptr[n] = sums[1023];
}

__global__ void fill_kernel(const int* __restrict__ src, const int* __restrict__ dst, int E,
                            int* __restrict__ cursor, int* __restrict__ edge_src) {
    int e = blockIdx.x * blockDim.x + threadIdx.x;
    if (e < E) {
        int d = dst[e];
        int pos = atomicAdd(&cursor[d], 1);
        edge_src[pos] = src[e];
    }
}

// ---------------------------------------------------------------------------
// Aggregation: Y[i,:] = dinv[i]^2 * X[i,:] + sum_{e: s->i} dinv[s]*dinv[i]*X[s,:]
// one block per node, C threads (C = 128 or 256)
// ---------------------------------------------------------------------------
__global__ void agg_kernel(const float* __restrict__ X, float* __restrict__ Y, int C,
                           const int* __restrict__ row_ptr, const int* __restrict__ edge_src,
                           const float* __restrict__ dinv) {
    int i = blockIdx.x;
    int c = threadIdx.x;
    float di = dinv[i];
    float acc = di * di * X[(size_t)i * C + c];
    int e0 = row_ptr[i], e1 = row_ptr[i + 1];
    for (int e = e0; e < e1; ++e) {
        int s = edge_src[e];
        float w = di * dinv[s];
        acc = fmaf(w, X[(size_t)s * C + c], acc);
    }
    Y[(size_t)i * C + c] = acc;
}

// ---------------------------------------------------------------------------
// fp32 GEMM: Y[r, cb+c] = act( sum_k X[r,k]*W[k,c_global] + bias[c_global] )
// 64x64 block tile, 4x4 per thread, K chunked by 64 through LDS.
// ---------------------------------------------------------------------------
__global__ __launch_bounds__(256)
void gemm_kernel(const float* __restrict__ X, int ldx,
                 const float* __restrict__ W, int ldw,
                 const float* __restrict__ bias,
                 float* __restrict__ Y, int ldy,
                 int nrows, int K, int relu) {
    __shared__ float Xs[64][68];  // [k][row]
    __shared__ float Ws[64][68];  // [k][col]
    const int tid = threadIdx.x;
    const int tx = tid & 15;
    const int ty = tid >> 4;
    const int rb = blockIdx.x * 64;
    const int cb = blockIdx.y * 64;

    float acc[4][4] = {{0.f}};

    for (int k0 = 0; k0 < K; k0 += 64) {
        // stage X tile (transposed to [k][row])
#pragma unroll
        for (int q = 0; q < 4; ++q) {
            int idx = tid + q * 256;     // 0..1023
            int row = idx >> 4;          // 0..63
            int kq  = idx & 15;          // 0..15 -> k = kq*4..kq*4+3
            float4 v = make_float4(0.f, 0.f, 0.f, 0.f);
            int r = rb + row;
            if (r < nrows) v = *(const float4*)&X[(size_t)r * ldx + k0 + kq * 4];
            Xs[kq * 4 + 0][row] = v.x;
            Xs[kq * 4 + 1][row] = v.y;
            Xs[kq * 4 + 2][row] = v.z;
            Xs[kq * 4 + 3][row] = v.w;
        }
        // stage W tile ([k][col], natural layout)
#pragma unroll
        for (int q = 0; q < 4; ++q) {
            int idx = tid + q * 256;
            int k  = idx >> 4;
            int c4 = idx & 15;
            float4 v = *(const float4*)&W[(size_t)(k0 + k) * ldw + cb + c4 * 4];
            *(float4*)&Ws[k][c4 * 4] = v;
        }
        __syncthreads();
#pragma unroll 16
        for (int k = 0; k < 64; ++k) {
            const float4 xv = *(const float4*)&Xs[k][ty * 4];
            const float4 wv = *(const float4*)&Ws[k][tx * 4];
            const float xr[4] = {xv.x, xv.y, xv.z, xv.w};
            const float wr[4] = {wv.x, wv.y, wv.z, wv.w};
#pragma unroll
            for (int i = 0; i < 4; ++i)
#pragma unroll
                for (int j = 0; j < 4; ++j)
                    acc[i][j] = fmaf(xr[i], wr[j], acc[i][j]);
        }
        __syncthreads();
    }

    const float4 bv = *(const float4*)&bias[cb + tx * 4];
    const float br[4] = {bv.x, bv.y, bv.z, bv.w};
#pragma unroll
    for (int i = 0; i < 4; ++i) {
        int r = rb + ty * 4 + i;
        if (r >= nrows) continue;
        float4 o;
        float v0 = acc[i][0] + br[0];
        float v1 = acc[i][1] + br[1];
        float v2 = acc[i][2] + br[2];
        float v3 = acc[i][3] + br[3];
        if (relu) {
            v0 = fmaxf(v0, 0.f); v1 = fmaxf(v1, 0.f);
            v2 = fmaxf(v2, 0.f); v3 = fmaxf(v3, 0.f);
        }
        o.x = v0; o.y = v1; o.z = v2; o.w = v3;
        *(float4*)&Y[(size_t)r * ldy + cb + tx * 4] = o;
    }
}

// ---------------------------------------------------------------------------
// Attention fusion: per node, 2-way softmax over (h1.Watt+b, h2.Watt+b),
// writes h_meta into comb[:,128:256]. One wave per node.
// ---------------------------------------------------------------------------
__global__ __launch_bounds__(64)
void attn_kernel(const float* __restrict__ h1, const float* __restrict__ h2,
                 const float* __restrict__ Watt, const float* __restrict__ batt,
                 float* __restrict__ out, int ldout) {
    int i = blockIdx.x;
    int l = threadIdx.x;
    float w0 = Watt[l], w1w = Watt[l + 64];
    float h1a = h1[(size_t)i * 128 + l],      h1b = h1[(size_t)i * 128 + l + 64];
    float h2a = h2[(size_t)i * 128 + l],      h2b = h2[(size_t)i * 128 + l + 64];
    float a = h1a * w0 + h1b * w1w;
    float b = h2a * w0 + h2b * w1w;
#pragma unroll
    for (int off = 32; off > 0; off >>= 1) {
        a += __shfl_xor(a, off);
        b += __shfl_xor(b, off);
    }
    float ba = batt[0];
    a += ba; b += ba;
    float m  = fmaxf(a, b);
    float ea = __expf(a - m), eb = __expf(b - m);
    float inv = 1.f / (ea + eb);
    float wa = ea * inv, wb = eb * inv;
    out[(size_t)i * ldout + l]      = wa * h1a + wb * h2a;
    out[(size_t)i * ldout + l + 64] = wa * h1b + wb * h2b;
}

// ---------------------------------------------------------------------------
extern "C" void kernel_launch(void* const* d_in, const int* in_sizes, int n_in,
                              void* d_out, int out_size, void* d_ws, size_t ws_size,
                              hipStream_t stream) {
    const int N = N_NODES, E = N_EDGES;
    const float* x     = (const float*)d_in[0];
    const int*   ei    = (const int*)d_in[1];
    const int*   esrc  = ei;
    const int*   edst  = ei + E;
    const float* W_s1  = (const float*)d_in[2];
    const float* b_s1  = (const float*)d_in[3];
    const float* W_s2  = (const float*)d_in[4];
    const float* b_s2  = (const float*)d_in[5];
    const float* W_m1  = (const float*)d_in[6];
    const float* b_m1  = (const float*)d_in[7];
    const float* W_m21 = (const float*)d_in[8];
    const float* b_m21 = (const float*)d_in[9];
    const float* W_m22 = (const float*)d_in[10];
    const float* b_m22 = (const float*)d_in[11];
    const float* W_att = (const float*)d_in[12];
    const float* b_att = (const float*)d_in[13];
    const float* W_fc  = (const float*)d_in[14];
    const float* b_fc  = (const float*)d_in[15];
    float* out = (float*)d_out;

    char* base = (char*)d_ws;
    size_t off = 0;
    auto take = [&](size_t nbytes) -> void* {
        void* p = base + off;
        off += (nbytes + 255) & ~(size_t)255;
        return p;
    };
    int*   hist     = (int*)take((size_t)N * 4);
    int*   cursor   = (int*)take((size_t)N * 4);
    int*   row_ptr  = (int*)take((size_t)(N + 1) * 4);
    int*   edge_src = (int*)take((size_t)E * 4);
    float* dinv     = (float*)take((size_t)N * 4);
    float* agg_x    = (float*)take((size_t)N * 128 * 4);   // S @ x
    float* bufA     = (float*)take((size_t)N * 256 * 4);   // [h_s1 | h2a] -> later comb [h_struct | h_meta]
    float* bufB     = (float*)take((size_t)N * 256 * 4);   // agg2 = S @ bufA
    float* h1buf    = (float*)take((size_t)N * 128 * 4);   // h1
    float* h2buf    = (float*)take((size_t)N * 128 * 4);   // h2

    // ---- CSR build + norms ----
    hipMemsetAsync(hist, 0, (size_t)N * 4, stream);
    degree_kernel<<<(E + 255) / 256, 256, 0, stream>>>(edst, E, hist);
    dinv_kernel<<<(N + 255) / 256, 256, 0, stream>>>(hist, dinv, N);
    scan_kernel<<<1, 1024, 0, stream>>>(hist, row_ptr, cursor, N);
    fill_kernel<<<(E + 255) / 256, 256, 0, stream>>>(esrc, edst, E, cursor, edge_src);

    // ---- layer 1: one aggregation feeds three GEMMs (GCN is linear) ----
    agg_kernel<<<N, 128, 0, stream>>>(x, agg_x, 128, row_ptr, edge_src, dinv);

    dim3 g128((N + 63) / 64, 2);
    dim3 g64((N + 63) / 64, 1);
    // h_s1 -> bufA[:, 0:128]
    gemm_kernel<<<g128, 256, 0, stream>>>(agg_x, 128, W_s1, 128, b_s1, bufA, 256, N, 128, 1);
    // h1 -> h1buf
    gemm_kernel<<<g128, 256, 0, stream>>>(agg_x, 128, W_m1, 128, b_m1, h1buf, 128, N, 128, 1);
    // h2a -> bufA[:, 128:256]
    gemm_kernel<<<g128, 256, 0, stream>>>(agg_x, 128, W_m21, 128, b_m21, bufA + 128, 256, N, 128, 1);

    // ---- layer 2: single 256-channel aggregation of [h_s1 | h2a] ----
    agg_kernel<<<N, 256, 0, stream>>>(bufA, bufB, 256, row_ptr, edge_src, dinv);

    // h_struct -> bufA[:, 0:128] (bufA contents dead after agg)
    gemm_kernel<<<g128, 256, 0, stream>>>(bufB, 256, W_s2, 128, b_s2, bufA, 256, N, 128, 1);
    // h2 -> h2buf
    gemm_kernel<<<g128, 256, 0, stream>>>(bufB + 128, 256, W_m22, 128, b_m22, h2buf, 128, N, 128, 1);

    // ---- attention fusion: h_meta -> bufA[:, 128:256] ----
    attn_kernel<<<N, 64, 0, stream>>>(h1buf, h2buf, W_att, b_att, bufA + 128, 256);

    // ---- final: out = comb @ W_fc + b_fc ----
    gemm_kernel<<<g64, 256, 0, stream>>>(bufA, 256, W_fc, 64, b_fc, out, 64, N, 256, 0);
}

// Round 2
// 672.284 us; speedup vs baseline: 1.1185x; 1.1185x over previous
//
#include <hip/hip_runtime.h>
#include <hip/hip_bf16.h>

#define N_NODES 50000
#define N_EDGES 800000
#define IN_C 128
#define HID_C 128
#define OUT_C 64

// ---------------------------------------------------------------------------
// CSR build: histogram of dst, exclusive scan -> row_ptr, fill (src, dinv[src])
// ---------------------------------------------------------------------------
__global__ void degree_kernel(const int* __restrict__ dst, int E, int* __restrict__ hist) {
    int e = blockIdx.x * blockDim.x + threadIdx.x;
    if (e < E) atomicAdd(&hist[dst[e]], 1);
}

__global__ void dinv_kernel(const int* __restrict__ hist, float* __restrict__ dinv, int n) {
    int i = blockIdx.x * blockDim.x + threadIdx.x;
    if (i < n) dinv[i] = rsqrtf((float)(hist[i] + 1));  // +1 self loop
}

__global__ __launch_bounds__(1024)
void scan_kernel(const int* __restrict__ hist, int* __restrict__ row_ptr,
                 int* __restrict__ cursor, int n) {
    __shared__ int sums[1024];
    int t = threadIdx.x;
    int chunk = (n + 1023) >> 10;
    int start = t * chunk;
    int end = min(start + chunk, n);
    int s = 0;
    for (int i = start; i < end; ++i) s += hist[i];
    sums[t] = s;
    __syncthreads();
    for (int off = 1; off < 1024; off <<= 1) {
        int v = (t >= off) ? sums[t - off] : 0;
        __syncthreads();
        sums[t] += v;
        __syncthreads();
    }
    int run = sums[t] - s;  // exclusive prefix of this thread's chunk
    for (int i = start; i < end; ++i) {
        row_ptr[i] = run;
        cursor[i]  = run;
        run += hist[i];
    }
    if (t == 1023) row_ptr[n] = sums[1023];
}

__global__ void fill_kernel(const int* __restrict__ src, const int* __restrict__ dst, int E,
                            int* __restrict__ cursor, int2* __restrict__ edge_data,
                            const float* __restrict__ dinv) {
    int e = blockIdx.x * blockDim.x + threadIdx.x;
    if (e < E) {
        int d = dst[e];
        int s = src[e];
        int pos = atomicAdd(&cursor[d], 1);
        edge_data[pos] = make_int2(s, __float_as_int(dinv[s]));
    }
}

// ---------------------------------------------------------------------------
// Aggregation: Y[i,:] = dinv[i]^2 * X[i,:] + sum_{e: s->i} dinv[s]*dinv[i]*X[s,:]
// One wave per node. 64 lanes x float4 = 256 floats per wave-load.
// For C=128: 2 edge-slots per wave (lanes 0-31 / 32-63), shfl-reduced at end.
// Edge weights (dinv[src]) pre-packed with the src index -> no dependent gather.
// ---------------------------------------------------------------------------
template<int C>
__global__ __launch_bounds__(256)
void agg_fast(const float* __restrict__ X, int ldx,
              float* __restrict__ Y, int ldy,
              const int* __restrict__ row_ptr,
              const int2* __restrict__ edge_data,
              const float* __restrict__ dinv, int n) {
    constexpr int CG = C / 4;       // float4 groups per row (32 or 64)
    constexpr int SLOTS = 64 / CG;  // 2 for C=128, 1 for C=256
    const int wid = blockIdx.x * (blockDim.x >> 6) + (threadIdx.x >> 6);
    if (wid >= n) return;
    const int lane = threadIdx.x & 63;
    const int cg = lane & (CG - 1);
    const int slot = lane / CG;

    const float di = dinv[wid];
    float4 acc = make_float4(0.f, 0.f, 0.f, 0.f);
    if (slot == 0) {
        const float w = di * di;
        const float4 v = *(const float4*)&X[(size_t)wid * ldx + cg * 4];
        acc.x = w * v.x; acc.y = w * v.y; acc.z = w * v.z; acc.w = w * v.w;
    }
    const int e0 = row_ptr[wid], e1 = row_ptr[wid + 1];
    int e = e0 + slot;
#pragma unroll 2
    for (; e + SLOTS < e1; e += 2 * SLOTS) {
        const int2 d0 = edge_data[e];
        const int2 d1 = edge_data[e + SLOTS];
        const float w0 = di * __int_as_float(d0.y);
        const float w1 = di * __int_as_float(d1.y);
        const float4 v0 = *(const float4*)&X[(size_t)d0.x * ldx + cg * 4];
        const float4 v1 = *(const float4*)&X[(size_t)d1.x * ldx + cg * 4];
        acc.x = fmaf(w0, v0.x, acc.x); acc.y = fmaf(w0, v0.y, acc.y);
        acc.z = fmaf(w0, v0.z, acc.z); acc.w = fmaf(w0, v0.w, acc.w);
        acc.x = fmaf(w1, v1.x, acc.x); acc.y = fmaf(w1, v1.y, acc.y);
        acc.z = fmaf(w1, v1.z, acc.z); acc.w = fmaf(w1, v1.w, acc.w);
    }
    if (e < e1) {
        const int2 d0 = edge_data[e];
        const float w0 = di * __int_as_float(d0.y);
        const float4 v0 = *(const float4*)&X[(size_t)d0.x * ldx + cg * 4];
        acc.x = fmaf(w0, v0.x, acc.x); acc.y = fmaf(w0, v0.y, acc.y);
        acc.z = fmaf(w0, v0.z, acc.z); acc.w = fmaf(w0, v0.w, acc.w);
    }
    if (SLOTS == 2) {
        acc.x += __shfl_xor(acc.x, 32);
        acc.y += __shfl_xor(acc.y, 32);
        acc.z += __shfl_xor(acc.z, 32);
        acc.w += __shfl_xor(acc.w, 32);
    }
    if (slot == 0) *(float4*)&Y[(size_t)wid * ldy + cg * 4] = acc;
}

// ---------------------------------------------------------------------------
// fp32 GEMM: Y[r, cb+c] = act( sum_k X[r,k]*W[k,c_global] + bias[c_global] )
// 64x64 block tile, 4x4 per thread, K chunked by 64 through LDS.
// ---------------------------------------------------------------------------
__global__ __launch_bounds__(256)
void gemm_kernel(const float* __restrict__ X, int ldx,
                 const float* __restrict__ W, int ldw,
                 const float* __restrict__ bias,
                 float* __restrict__ Y, int ldy,
                 int nrows, int K, int relu) {
    __shared__ float Xs[64][68];  // [k][row]
    __shared__ float Ws[64][68];  // [k][col]
    const int tid = threadIdx.x;
    const int tx = tid & 15;
    const int ty = tid >> 4;
    const int rb = blockIdx.x * 64;
    const int cb = blockIdx.y * 64;

    float acc[4][4] = {{0.f}};

    for (int k0 = 0; k0 < K; k0 += 64) {
        // stage X tile (transposed to [k][row])
#pragma unroll
        for (int q = 0; q < 4; ++q) {
            int idx = tid + q * 256;     // 0..1023
            int row = idx >> 4;          // 0..63
            int kq  = idx & 15;          // 0..15 -> k = kq*4..kq*4+3
            float4 v = make_float4(0.f, 0.f, 0.f, 0.f);
            int r = rb + row;
            if (r < nrows) v = *(const float4*)&X[(size_t)r * ldx + k0 + kq * 4];
            Xs[kq * 4 + 0][row] = v.x;
            Xs[kq * 4 + 1][row] = v.y;
            Xs[kq * 4 + 2][row] = v.z;
            Xs[kq * 4 + 3][row] = v.w;
        }
        // stage W tile ([k][col], natural layout)
#pragma unroll
        for (int q = 0; q < 4; ++q) {
            int idx = tid + q * 256;
            int k  = idx >> 4;
            int c4 = idx & 15;
            float4 v = *(const float4*)&W[(size_t)(k0 + k) * ldw + cb + c4 * 4];
            *(float4*)&Ws[k][c4 * 4] = v;
        }
        __syncthreads();
#pragma unroll 16
        for (int k = 0; k < 64; ++k) {
            const float4 xv = *(const float4*)&Xs[k][ty * 4];
            const float4 wv = *(const float4*)&Ws[k][tx * 4];
            const float xr[4] = {xv.x, xv.y, xv.z, xv.w};
            const float wr[4] = {wv.x, wv.y, wv.z, wv.w};
#pragma unroll
            for (int i = 0; i < 4; ++i)
#pragma unroll
                for (int j = 0; j < 4; ++j)
                    acc[i][j] = fmaf(xr[i], wr[j], acc[i][j]);
        }
        __syncthreads();
    }

    const float4 bv = *(const float4*)&bias[cb + tx * 4];
    const float br[4] = {bv.x, bv.y, bv.z, bv.w};
#pragma unroll
    for (int i = 0; i < 4; ++i) {
        int r = rb + ty * 4 + i;
        if (r >= nrows) continue;
        float4 o;
        float v0 = acc[i][0] + br[0];
        float v1 = acc[i][1] + br[1];
        float v2 = acc[i][2] + br[2];
        float v3 = acc[i][3] + br[3];
        if (relu) {
            v0 = fmaxf(v0, 0.f); v1 = fmaxf(v1, 0.f);
            v2 = fmaxf(v2, 0.f); v3 = fmaxf(v3, 0.f);
        }
        o.x = v0; o.y = v1; o.z = v2; o.w = v3;
        *(float4*)&Y[(size_t)r * ldy + cb + tx * 4] = o;
    }
}

// ---------------------------------------------------------------------------
// Attention fusion: per node, 2-way softmax over (h1.Watt+b, h2.Watt+b),
// writes h_meta into comb[:,128:256]. One wave per node.
// ---------------------------------------------------------------------------
__global__ __launch_bounds__(64)
void attn_kernel(const float* __restrict__ h1, const float* __restrict__ h2,
                 const float* __restrict__ Watt, const float* __restrict__ batt,
                 float* __restrict__ out, int ldout) {
    int i = blockIdx.x;
    int l = threadIdx.x;
    float w0 = Watt[l], w1w = Watt[l + 64];
    float h1a = h1[(size_t)i * 128 + l],      h1b = h1[(size_t)i * 128 + l + 64];
    float h2a = h2[(size_t)i * 128 + l],      h2b = h2[(size_t)i * 128 + l + 64];
    float a = h1a * w0 + h1b * w1w;
    float b = h2a * w0 + h2b * w1w;
#pragma unroll
    for (int off = 32; off > 0; off >>= 1) {
        a += __shfl_xor(a, off);
        b += __shfl_xor(b, off);
    }
    float ba = batt[0];
    a += ba; b += ba;
    float m  = fmaxf(a, b);
    float ea = __expf(a - m), eb = __expf(b - m);
    float inv = 1.f / (ea + eb);
    float wa = ea * inv, wb = eb * inv;
    out[(size_t)i * ldout + l]      = wa * h1a + wb * h2a;
    out[(size_t)i * ldout + l + 64] = wa * h1b + wb * h2b;
}

// ---------------------------------------------------------------------------
extern "C" void kernel_launch(void* const* d_in, const int* in_sizes, int n_in,
                              void* d_out, int out_size, void* d_ws, size_t ws_size,
                              hipStream_t stream) {
    const int N = N_NODES, E = N_EDGES;
    const float* x     = (const float*)d_in[0];
    const int*   ei    = (const int*)d_in[1];
    const int*   esrc  = ei;
    const int*   edst  = ei + E;
    const float* W_s1  = (const float*)d_in[2];
    const float* b_s1  = (const float*)d_in[3];
    const float* W_s2  = (const float*)d_in[4];
    const float* b_s2  = (const float*)d_in[5];
    const float* W_m1  = (const float*)d_in[6];
    const float* b_m1  = (const float*)d_in[7];
    const float* W_m21 = (const float*)d_in[8];
    const float* b_m21 = (const float*)d_in[9];
    const float* W_m22 = (const float*)d_in[10];
    const float* b_m22 = (const float*)d_in[11];
    const float* W_att = (const float*)d_in[12];
    const float* b_att = (const float*)d_in[13];
    const float* W_fc  = (const float*)d_in[14];
    const float* b_fc  = (const float*)d_in[15];
    float* out = (float*)d_out;

    char* base = (char*)d_ws;
    size_t off = 0;
    auto take = [&](size_t nbytes) -> void* {
        void* p = base + off;
        off += (nbytes + 255) & ~(size_t)255;
        return p;
    };
    int*   hist      = (int*)take((size_t)N * 4);
    int*   cursor    = (int*)take((size_t)N * 4);
    int*   row_ptr   = (int*)take((size_t)(N + 1) * 4);
    int2*  edge_data = (int2*)take((size_t)E * 8);
    float* dinv      = (float*)take((size_t)N * 4);
    float* agg_x     = (float*)take((size_t)N * 128 * 4);   // S @ x
    float* bufA      = (float*)take((size_t)N * 256 * 4);   // [h_s1 | h2a] -> later comb
    float* bufB      = (float*)take((size_t)N * 256 * 4);   // agg2 = S @ bufA
    float* h1buf     = (float*)take((size_t)N * 128 * 4);   // h1
    float* h2buf     = (float*)take((size_t)N * 128 * 4);   // h2

    // ---- CSR build + norms ----
    hipMemsetAsync(hist, 0, (size_t)N * 4, stream);
    degree_kernel<<<(E + 255) / 256, 256, 0, stream>>>(edst, E, hist);
    dinv_kernel<<<(N + 255) / 256, 256, 0, stream>>>(hist, dinv, N);
    scan_kernel<<<1, 1024, 0, stream>>>(hist, row_ptr, cursor, N);
    fill_kernel<<<(E + 255) / 256, 256, 0, stream>>>(esrc, edst, E, cursor, edge_data, dinv);

    // ---- layer 1: one aggregation feeds three GEMMs (GCN is linear) ----
    agg_fast<128><<<(N + 3) / 4, 256, 0, stream>>>(x, 128, agg_x, 128, row_ptr, edge_data, dinv, N);

    dim3 g128((N + 63) / 64, 2);
    dim3 g64((N + 63) / 64, 1);
    // h_s1 -> bufA[:, 0:128]
    gemm_kernel<<<g128, 256, 0, stream>>>(agg_x, 128, W_s1, 128, b_s1, bufA, 256, N, 128, 1);
    // h1 -> h1buf
    gemm_kernel<<<g128, 256, 0, stream>>>(agg_x, 128, W_m1, 128, b_m1, h1buf, 128, N, 128, 1);
    // h2a -> bufA[:, 128:256]
    gemm_kernel<<<g128, 256, 0, stream>>>(agg_x, 128, W_m21, 128, b_m21, bufA + 128, 256, N, 128, 1);

    // ---- layer 2: single 256-channel aggregation of [h_s1 | h2a] ----
    agg_fast<256><<<(N + 3) / 4, 256, 0, stream>>>(bufA, 256, bufB, 256, row_ptr, edge_data, dinv, N);

    // h_struct -> bufA[:, 0:128] (bufA contents dead after agg)
    gemm_kernel<<<g128, 256, 0, stream>>>(bufB, 256, W_s2, 128, b_s2, bufA, 256, N, 128, 1);
    // h2 -> h2buf
    gemm_kernel<<<g128, 256, 0, stream>>>(bufB + 128, 256, W_m22, 128, b_m22, h2buf, 128, N, 128, 1);

    // ---- attention fusion: h_meta -> bufA[:, 128:256] ----
    attn_kernel<<<N, 64, 0, stream>>>(h1buf, h2buf, W_att, b_att, bufA + 128, 256);

    // ---- final: out = comb @ W_fc + b_fc ----
    gemm_kernel<<<g64, 256, 0, stream>>>(bufA, 256, W_fc, 64, b_fc, out, 64, N, 256, 0);
}

// Round 3
// 595.566 us; speedup vs baseline: 1.2626x; 1.1288x over previous
//
#include <hip/hip_runtime.h>
#include <hip/hip_bf16.h>

#define N_NODES 50000
#define N_EDGES 800000
#define IN_C 128
#define HID_C 128
#define OUT_C 64

__device__ __forceinline__ ushort f2bf(float f) {
    unsigned u = __float_as_uint(f);
    return (ushort)((u + 0x7fffu + ((u >> 16) & 1u)) >> 16);
}
__device__ __forceinline__ float bf2f(ushort u) {
    return __uint_as_float(((unsigned)u) << 16);
}

// ---------------------------------------------------------------------------
// CSR build: histogram of dst, exclusive scan -> row_ptr, fill (src, dinv[src])
// ---------------------------------------------------------------------------
__global__ void degree_kernel(const int* __restrict__ dst, int E, int* __restrict__ hist) {
    int e = blockIdx.x * blockDim.x + threadIdx.x;
    if (e < E) atomicAdd(&hist[dst[e]], 1);
}

__global__ void dinv_kernel(const int* __restrict__ hist, float* __restrict__ dinv, int n) {
    int i = blockIdx.x * blockDim.x + threadIdx.x;
    if (i < n) dinv[i] = rsqrtf((float)(hist[i] + 1));  // +1 self loop
}

__global__ __launch_bounds__(1024)
void scan_kernel(const int* __restrict__ hist, int* __restrict__ row_ptr,
                 int* __restrict__ cursor, int n) {
    __shared__ int sums[1024];
    int t = threadIdx.x;
    int chunk = (n + 1023) >> 10;
    int start = t * chunk;
    int end = min(start + chunk, n);
    int s = 0;
    for (int i = start; i < end; ++i) s += hist[i];
    sums[t] = s;
    __syncthreads();
    for (int off = 1; off < 1024; off <<= 1) {
        int v = (t >= off) ? sums[t - off] : 0;
        __syncthreads();
        sums[t] += v;
        __syncthreads();
    }
    int run = sums[t] - s;
    for (int i = start; i < end; ++i) {
        row_ptr[i] = run;
        cursor[i]  = run;
        run += hist[i];
    }
    if (t == 1023) row_ptr[n] = sums[1023];
}

__global__ void fill_kernel(const int* __restrict__ src, const int* __restrict__ dst, int E,
                            int* __restrict__ cursor, int2* __restrict__ edge_data,
                            const float* __restrict__ dinv) {
    int e = blockIdx.x * blockDim.x + threadIdx.x;
    if (e < E) {
        int d = dst[e];
        int s = src[e];
        int pos = atomicAdd(&cursor[d], 1);
        edge_data[pos] = make_int2(s, __float_as_int(dinv[s]));
    }
}

// ---------------------------------------------------------------------------
// fp32 -> bf16 conversion (RNE), 4 floats -> 2 uints per thread
// ---------------------------------------------------------------------------
__global__ void cvt_bf16_kernel(const float* __restrict__ in, uint2* __restrict__ out, int n4) {
    int i = blockIdx.x * blockDim.x + threadIdx.x;
    if (i >= n4) return;
    float4 v = *(const float4*)&in[(size_t)i * 4];
    uint2 o;
    o.x = (uint)f2bf(v.x) | ((uint)f2bf(v.y) << 16);
    o.y = (uint)f2bf(v.z) | ((uint)f2bf(v.w) << 16);
    out[i] = o;
}

// ---------------------------------------------------------------------------
// Pack Wcat = [W_s1 | W_m21 | W_m1] (128 x 384), bcat likewise
// ---------------------------------------------------------------------------
__global__ void pack_w_kernel(const float* __restrict__ W_s1, const float* __restrict__ W_m21,
                              const float* __restrict__ W_m1,
                              const float* __restrict__ b_s1, const float* __restrict__ b_m21,
                              const float* __restrict__ b_m1,
                              float* __restrict__ Wcat, float* __restrict__ bcat) {
    int idx = blockIdx.x * blockDim.x + threadIdx.x;
    if (idx < 128 * 384) {
        int k = idx / 384, c = idx % 384;
        float v = (c < 128) ? W_s1[k * 128 + c]
                : (c < 256) ? W_m21[k * 128 + (c - 128)]
                            : W_m1[k * 128 + (c - 256)];
        Wcat[idx] = v;
    }
    if (idx < 384) {
        bcat[idx] = (idx < 128) ? b_s1[idx] : (idx < 256) ? b_m21[idx - 128] : b_m1[idx - 256];
    }
}

// ---------------------------------------------------------------------------
// bf16-gather aggregation:
// Y[i,:] = dinv[i]^2 * X[i,:] + sum_{e: s->i} dinv[s]*dinv[i]*X[s,:]   (fp32 out)
// One wave per node; each lane covers 8 channels (uint4 = 8 bf16).
// C=256: 2 edge slots/wave; C=128: 4 edge slots/wave. Manual 2x unroll
// -> 4-8 gather rows in flight per wave.
// ---------------------------------------------------------------------------
template<int C>
__global__ __launch_bounds__(256)
void agg_bf16(const ushort* __restrict__ X, int ldx,
              float* __restrict__ Y, int ldy,
              const int* __restrict__ row_ptr,
              const int2* __restrict__ edge_data,
              const float* __restrict__ dinv, int n) {
    constexpr int CG = C / 8;       // lanes per row
    constexpr int SLOTS = 64 / CG;  // 2 for C=256, 4 for C=128
    const int wid = blockIdx.x * (blockDim.x >> 6) + (threadIdx.x >> 6);
    if (wid >= n) return;
    const int lane = threadIdx.x & 63;
    const int cg = lane & (CG - 1);
    const int slot = lane / CG;

    const float di = dinv[wid];
    float acc[8] = {0.f, 0.f, 0.f, 0.f, 0.f, 0.f, 0.f, 0.f};

    auto fma_row = [&](uint4 v, float w) {
        acc[0] = fmaf(w, __uint_as_float(v.x << 16), acc[0]);
        acc[1] = fmaf(w, __uint_as_float(v.x & 0xffff0000u), acc[1]);
        acc[2] = fmaf(w, __uint_as_float(v.y << 16), acc[2]);
        acc[3] = fmaf(w, __uint_as_float(v.y & 0xffff0000u), acc[3]);
        acc[4] = fmaf(w, __uint_as_float(v.z << 16), acc[4]);
        acc[5] = fmaf(w, __uint_as_float(v.z & 0xffff0000u), acc[5]);
        acc[6] = fmaf(w, __uint_as_float(v.w << 16), acc[6]);
        acc[7] = fmaf(w, __uint_as_float(v.w & 0xffff0000u), acc[7]);
    };

    if (slot == 0) {
        uint4 v = *(const uint4*)&X[(size_t)wid * ldx + cg * 8];
        fma_row(v, di * di);
    }
    const int e0 = row_ptr[wid], e1 = row_ptr[wid + 1];
    int e = e0 + slot;
    for (; e + SLOTS < e1; e += 2 * SLOTS) {
        const int2 d0 = edge_data[e];
        const int2 d1 = edge_data[e + SLOTS];
        const uint4 v0 = *(const uint4*)&X[(size_t)d0.x * ldx + cg * 8];
        const uint4 v1 = *(const uint4*)&X[(size_t)d1.x * ldx + cg * 8];
        fma_row(v0, di * __int_as_float(d0.y));
        fma_row(v1, di * __int_as_float(d1.y));
    }
    if (e < e1) {
        const int2 d0 = edge_data[e];
        const uint4 v0 = *(const uint4*)&X[(size_t)d0.x * ldx + cg * 8];
        fma_row(v0, di * __int_as_float(d0.y));
    }
#pragma unroll
    for (int j = 0; j < 8; ++j) {
        if (SLOTS == 4) acc[j] += __shfl_xor(acc[j], 16);
        if (SLOTS >= 2) acc[j] += __shfl_xor(acc[j], 32);
    }
    if (slot == 0) {
        float* dst = &Y[(size_t)wid * ldy + cg * 8];
        *(float4*)&dst[0] = make_float4(acc[0], acc[1], acc[2], acc[3]);
        *(float4*)&dst[4] = make_float4(acc[4], acc[5], acc[6], acc[7]);
    }
}

// ---------------------------------------------------------------------------
// fp32 GEMM: Y[r, cb+c] = act( sum_k X[r,k]*W[k,c] + bias[c] )
// 64x64 block tile, 4x4 per thread, K chunked by 64 through LDS.
// obf16 != 0 -> Y is ushort* (bf16 RNE), else float*.
// ---------------------------------------------------------------------------
__global__ __launch_bounds__(256)
void gemm_kernel(const float* __restrict__ X, int ldx,
                 const float* __restrict__ W, int ldw,
                 const float* __restrict__ bias,
                 void* __restrict__ Yv, int ldy,
                 int nrows, int K, int relu, int obf16) {
    __shared__ float Xs[64][68];  // [k][row]
    __shared__ float Ws[64][68];  // [k][col]
    const int tid = threadIdx.x;
    const int tx = tid & 15;
    const int ty = tid >> 4;
    const int rb = blockIdx.x * 64;
    const int cb = blockIdx.y * 64;

    float acc[4][4] = {{0.f}};

    for (int k0 = 0; k0 < K; k0 += 64) {
#pragma unroll
        for (int q = 0; q < 4; ++q) {
            int idx = tid + q * 256;
            int row = idx >> 4;
            int kq  = idx & 15;
            float4 v = make_float4(0.f, 0.f, 0.f, 0.f);
            int r = rb + row;
            if (r < nrows) v = *(const float4*)&X[(size_t)r * ldx + k0 + kq * 4];
            Xs[kq * 4 + 0][row] = v.x;
            Xs[kq * 4 + 1][row] = v.y;
            Xs[kq * 4 + 2][row] = v.z;
            Xs[kq * 4 + 3][row] = v.w;
        }
#pragma unroll
        for (int q = 0; q < 4; ++q) {
            int idx = tid + q * 256;
            int k  = idx >> 4;
            int c4 = idx & 15;
            float4 v = *(const float4*)&W[(size_t)(k0 + k) * ldw + cb + c4 * 4];
            *(float4*)&Ws[k][c4 * 4] = v;
        }
        __syncthreads();
#pragma unroll 16
        for (int k = 0; k < 64; ++k) {
            const float4 xv = *(const float4*)&Xs[k][ty * 4];
            const float4 wv = *(const float4*)&Ws[k][tx * 4];
            const float xr[4] = {xv.x, xv.y, xv.z, xv.w};
            const float wr[4] = {wv.x, wv.y, wv.z, wv.w};
#pragma unroll
            for (int i = 0; i < 4; ++i)
#pragma unroll
                for (int j = 0; j < 4; ++j)
                    acc[i][j] = fmaf(xr[i], wr[j], acc[i][j]);
        }
        __syncthreads();
    }

    const float4 bv = *(const float4*)&bias[cb + tx * 4];
    const float br[4] = {bv.x, bv.y, bv.z, bv.w};
#pragma unroll
    for (int i = 0; i < 4; ++i) {
        int r = rb + ty * 4 + i;
        if (r >= nrows) continue;
        float v0 = acc[i][0] + br[0];
        float v1 = acc[i][1] + br[1];
        float v2 = acc[i][2] + br[2];
        float v3 = acc[i][3] + br[3];
        if (relu) {
            v0 = fmaxf(v0, 0.f); v1 = fmaxf(v1, 0.f);
            v2 = fmaxf(v2, 0.f); v3 = fmaxf(v3, 0.f);
        }
        if (obf16) {
            ushort4 o;
            o.x = f2bf(v0); o.y = f2bf(v1); o.z = f2bf(v2); o.w = f2bf(v3);
            *(ushort4*)&((ushort*)Yv)[(size_t)r * ldy + cb + tx * 4] = o;
        } else {
            *(float4*)&((float*)Yv)[(size_t)r * ldy + cb + tx * 4] = make_float4(v0, v1, v2, v3);
        }
    }
}

// ---------------------------------------------------------------------------
// Attention fusion: per node, 2-way softmax over (h1.Watt+b, h2.Watt+b).
// h1 is bf16 (cols 256:384 of cat1, ld=384), h2 is fp32.
// ---------------------------------------------------------------------------
__global__ __launch_bounds__(64)
void attn_kernel(const ushort* __restrict__ h1bf, const float* __restrict__ h2,
                 const float* __restrict__ Watt, const float* __restrict__ batt,
                 float* __restrict__ out, int ldout) {
    int i = blockIdx.x;
    int l = threadIdx.x;
    const ushort* h1p = &h1bf[(size_t)i * 384 + 256];
    float w0 = Watt[l], w1w = Watt[l + 64];
    float h1a = bf2f(h1p[l]),               h1b = bf2f(h1p[l + 64]);
    float h2a = h2[(size_t)i * 128 + l],    h2b = h2[(size_t)i * 128 + l + 64];
    float a = h1a * w0 + h1b * w1w;
    float b = h2a * w0 + h2b * w1w;
#pragma unroll
    for (int off = 32; off > 0; off >>= 1) {
        a += __shfl_xor(a, off);
        b += __shfl_xor(b, off);
    }
    float ba = batt[0];
    a += ba; b += ba;
    float m  = fmaxf(a, b);
    float ea = __expf(a - m), eb = __expf(b - m);
    float inv = 1.f / (ea + eb);
    float wa = ea * inv, wb = eb * inv;
    out[(size_t)i * ldout + l]      = wa * h1a + wb * h2a;
    out[(size_t)i * ldout + l + 64] = wa * h1b + wb * h2b;
}

// ---------------------------------------------------------------------------
extern "C" void kernel_launch(void* const* d_in, const int* in_sizes, int n_in,
                              void* d_out, int out_size, void* d_ws, size_t ws_size,
                              hipStream_t stream) {
    const int N = N_NODES, E = N_EDGES;
    const float* x     = (const float*)d_in[0];
    const int*   ei    = (const int*)d_in[1];
    const int*   esrc  = ei;
    const int*   edst  = ei + E;
    const float* W_s1  = (const float*)d_in[2];
    const float* b_s1  = (const float*)d_in[3];
    const float* W_s2  = (const float*)d_in[4];
    const float* b_s2  = (const float*)d_in[5];
    const float* W_m1  = (const float*)d_in[6];
    const float* b_m1  = (const float*)d_in[7];
    const float* W_m21 = (const float*)d_in[8];
    const float* b_m21 = (const float*)d_in[9];
    const float* W_m22 = (const float*)d_in[10];
    const float* b_m22 = (const float*)d_in[11];
    const float* W_att = (const float*)d_in[12];
    const float* b_att = (const float*)d_in[13];
    const float* W_fc  = (const float*)d_in[14];
    const float* b_fc  = (const float*)d_in[15];
    float* out = (float*)d_out;

    char* base = (char*)d_ws;
    size_t off = 0;
    auto take = [&](size_t nbytes) -> void* {
        void* p = base + off;
        off += (nbytes + 255) & ~(size_t)255;
        return p;
    };
    int*    hist      = (int*)take((size_t)N * 4);
    int*    cursor    = (int*)take((size_t)N * 4);
    int*    row_ptr   = (int*)take((size_t)(N + 1) * 4);
    int2*   edge_data = (int2*)take((size_t)E * 8);
    float*  dinv      = (float*)take((size_t)N * 4);
    ushort* xb        = (ushort*)take((size_t)N * 128 * 2);   // x in bf16
    float*  agg_x     = (float*)take((size_t)N * 128 * 4);    // S @ x (fp32)
    ushort* cat1      = (ushort*)take((size_t)N * 384 * 2);   // [h_s1 | h2a | h1] bf16
    float*  bufB      = (float*)take((size_t)N * 256 * 4);    // S @ cat1[:,0:256]
    float*  comb      = (float*)take((size_t)N * 256 * 4);    // [h_struct | h_meta]
    float*  h2buf     = (float*)take((size_t)N * 128 * 4);    // h2 fp32
    float*  Wcat      = (float*)take((size_t)128 * 384 * 4);
    float*  bcat      = (float*)take((size_t)384 * 4);

    // ---- CSR build + norms ----
    hipMemsetAsync(hist, 0, (size_t)N * 4, stream);
    degree_kernel<<<(E + 255) / 256, 256, 0, stream>>>(edst, E, hist);
    dinv_kernel<<<(N + 255) / 256, 256, 0, stream>>>(hist, dinv, N);
    scan_kernel<<<1, 1024, 0, stream>>>(hist, row_ptr, cursor, N);
    fill_kernel<<<(E + 255) / 256, 256, 0, stream>>>(esrc, edst, E, cursor, edge_data, dinv);

    // ---- prep: x -> bf16; pack fused layer-1 weights ----
    cvt_bf16_kernel<<<(N * 128 / 4 + 255) / 256, 256, 0, stream>>>(x, (uint2*)xb, N * 128 / 4);
    pack_w_kernel<<<(128 * 384 + 255) / 256, 256, 0, stream>>>(W_s1, W_m21, W_m1,
                                                               b_s1, b_m21, b_m1, Wcat, bcat);

    // ---- layer 1: one bf16 aggregation feeds one fused GEMM ----
    agg_bf16<128><<<(N + 3) / 4, 256, 0, stream>>>(xb, 128, agg_x, 128, row_ptr, edge_data, dinv, N);

    dim3 g384((N + 63) / 64, 6);
    dim3 g128((N + 63) / 64, 2);
    dim3 g64((N + 63) / 64, 1);
    // cat1 = relu(agg_x @ [W_s1|W_m21|W_m1] + bcat), bf16 out
    gemm_kernel<<<g384, 256, 0, stream>>>(agg_x, 128, Wcat, 384, bcat, cat1, 384, N, 128, 1, 1);

    // ---- layer 2: one 256-channel bf16 aggregation of [h_s1 | h2a] ----
    agg_bf16<256><<<(N + 3) / 4, 256, 0, stream>>>(cat1, 384, bufB, 256, row_ptr, edge_data, dinv, N);

    // h_struct -> comb[:, 0:128]
    gemm_kernel<<<g128, 256, 0, stream>>>(bufB, 256, W_s2, 128, b_s2, comb, 256, N, 128, 1, 0);
    // h2 -> h2buf
    gemm_kernel<<<g128, 256, 0, stream>>>(bufB + 128, 256, W_m22, 128, b_m22, h2buf, 128, N, 128, 1, 0);

    // ---- attention fusion: h_meta -> comb[:, 128:256] ----
    attn_kernel<<<N, 64, 0, stream>>>(cat1, h2buf, W_att, b_att, comb + 128, 256);

    // ---- final: out = comb @ W_fc + b_fc ----
    gemm_kernel<<<g64, 256, 0, stream>>>(comb, 256, W_fc, 64, b_fc, out, 64, N, 256, 0, 0);
}

// Round 4
// 490.872 us; speedup vs baseline: 1.5319x; 1.2133x over previous
//
#include <hip/hip_runtime.h>
#include <hip/hip_bf16.h>

#define N_NODES 50000
#define N_EDGES 800000
#define IN_C 128
#define HID_C 128
#define OUT_C 64

#define SCAN_BS 256
#define SCAN_NB ((N_NODES + SCAN_BS - 1) / SCAN_BS)   // 196

__device__ __forceinline__ ushort f2bf(float f) {
    unsigned u = __float_as_uint(f);
    return (ushort)((u + 0x7fffu + ((u >> 16) & 1u)) >> 16);
}
__device__ __forceinline__ float bf2f(ushort u) {
    return __uint_as_float(((unsigned)u) << 16);
}

// ---------------------------------------------------------------------------
// CSR build: histogram of dst, 3-phase scan -> row_ptr, fill (src, dinv[src])
// ---------------------------------------------------------------------------
__global__ void degree_kernel(const int* __restrict__ dst, int E, int* __restrict__ hist) {
    int e = blockIdx.x * blockDim.x + threadIdx.x;
    if (e < E) atomicAdd(&hist[dst[e]], 1);
}

__global__ void dinv_kernel(const int* __restrict__ hist, float* __restrict__ dinv, int n) {
    int i = blockIdx.x * blockDim.x + threadIdx.x;
    if (i < n) dinv[i] = rsqrtf((float)(hist[i] + 1));  // +1 self loop
}

// phase 1: per-block sums of hist
__global__ __launch_bounds__(SCAN_BS)
void scan1_kernel(const int* __restrict__ hist, int* __restrict__ bsum, int n) {
    __shared__ int s[SCAN_BS];
    int t = threadIdx.x;
    int i = blockIdx.x * SCAN_BS + t;
    int v = (i < n) ? hist[i] : 0;
    s[t] = v;
    __syncthreads();
#pragma unroll
    for (int off = SCAN_BS / 2; off > 0; off >>= 1) {
        if (t < off) s[t] += s[t + off];
        __syncthreads();
    }
    if (t == 0) bsum[blockIdx.x] = s[0];
}

// phase 2: single block exclusive-scans the block sums (nb <= SCAN_BS)
__global__ __launch_bounds__(SCAN_BS)
void scan2_kernel(int* __restrict__ bsum, int* __restrict__ bpre, int nb,
                  int* __restrict__ row_ptr_last, int n) {
    __shared__ int s[SCAN_BS];
    int t = threadIdx.x;
    int v = (t < nb) ? bsum[t] : 0;
    s[t] = v;
    __syncthreads();
#pragma unroll
    for (int off = 1; off < SCAN_BS; off <<= 1) {
        int tmp = (t >= off) ? s[t - off] : 0;
        __syncthreads();
        s[t] += tmp;
        __syncthreads();
    }
    if (t < nb) bpre[t] = s[t] - v;              // exclusive prefix
    if (t == SCAN_BS - 1) row_ptr_last[n] = s[t]; // total = E
}

// phase 3: per-block exclusive scan + block offset -> row_ptr & cursor
__global__ __launch_bounds__(SCAN_BS)
void scan3_kernel(const int* __restrict__ hist, const int* __restrict__ bpre,
                  int* __restrict__ row_ptr, int* __restrict__ cursor, int n) {
    __shared__ int s[SCAN_BS];
    int t = threadIdx.x;
    int i = blockIdx.x * SCAN_BS + t;
    int v = (i < n) ? hist[i] : 0;
    s[t] = v;
    __syncthreads();
#pragma unroll
    for (int off = 1; off < SCAN_BS; off <<= 1) {
        int tmp = (t >= off) ? s[t - off] : 0;
        __syncthreads();
        s[t] += tmp;
        __syncthreads();
    }
    if (i < n) {
        int ex = s[t] - v + bpre[blockIdx.x];
        row_ptr[i] = ex;
        cursor[i]  = ex;
    }
}

__global__ void fill_kernel(const int* __restrict__ src, const int* __restrict__ dst, int E,
                            int* __restrict__ cursor, int2* __restrict__ edge_data,
                            const float* __restrict__ dinv) {
    int e = blockIdx.x * blockDim.x + threadIdx.x;
    if (e < E) {
        int d = dst[e];
        int s = src[e];
        int pos = atomicAdd(&cursor[d], 1);
        edge_data[pos] = make_int2(s, __float_as_int(dinv[s]));
    }
}

// ---------------------------------------------------------------------------
// fp32 -> bf16 conversion (RNE), 4 floats -> 2 uints per thread
// ---------------------------------------------------------------------------
__global__ void cvt_bf16_kernel(const float* __restrict__ in, uint2* __restrict__ out, int n4) {
    int i = blockIdx.x * blockDim.x + threadIdx.x;
    if (i >= n4) return;
    float4 v = *(const float4*)&in[(size_t)i * 4];
    uint2 o;
    o.x = (uint)f2bf(v.x) | ((uint)f2bf(v.y) << 16);
    o.y = (uint)f2bf(v.z) | ((uint)f2bf(v.w) << 16);
    out[i] = o;
}

// ---------------------------------------------------------------------------
// Pack Wcat = [W_s1 | W_m21 | W_m1] (128 x 384), bcat likewise
// ---------------------------------------------------------------------------
__global__ void pack_w_kernel(const float* __restrict__ W_s1, const float* __restrict__ W_m21,
                              const float* __restrict__ W_m1,
                              const float* __restrict__ b_s1, const float* __restrict__ b_m21,
                              const float* __restrict__ b_m1,
                              float* __restrict__ Wcat, float* __restrict__ bcat) {
    int idx = blockIdx.x * blockDim.x + threadIdx.x;
    if (idx < 128 * 384) {
        int k = idx / 384, c = idx % 384;
        float v = (c < 128) ? W_s1[k * 128 + c]
                : (c < 256) ? W_m21[k * 128 + (c - 128)]
                            : W_m1[k * 128 + (c - 256)];
        Wcat[idx] = v;
    }
    if (idx < 384) {
        bcat[idx] = (idx < 128) ? b_s1[idx] : (idx < 256) ? b_m21[idx - 128] : b_m1[idx - 256];
    }
}

// ---------------------------------------------------------------------------
// bf16-gather aggregation (fp32 accumulate/out). One wave per node.
// ---------------------------------------------------------------------------
template<int C>
__global__ __launch_bounds__(256)
void agg_bf16(const ushort* __restrict__ X, int ldx,
              float* __restrict__ Y, int ldy,
              const int* __restrict__ row_ptr,
              const int2* __restrict__ edge_data,
              const float* __restrict__ dinv, int n) {
    constexpr int CG = C / 8;       // lanes per row
    constexpr int SLOTS = 64 / CG;  // 2 for C=256, 4 for C=128
    const int wid = blockIdx.x * (blockDim.x >> 6) + (threadIdx.x >> 6);
    if (wid >= n) return;
    const int lane = threadIdx.x & 63;
    const int cg = lane & (CG - 1);
    const int slot = lane / CG;

    const float di = dinv[wid];
    float acc[8] = {0.f, 0.f, 0.f, 0.f, 0.f, 0.f, 0.f, 0.f};

    auto fma_row = [&](uint4 v, float w) {
        acc[0] = fmaf(w, __uint_as_float(v.x << 16), acc[0]);
        acc[1] = fmaf(w, __uint_as_float(v.x & 0xffff0000u), acc[1]);
        acc[2] = fmaf(w, __uint_as_float(v.y << 16), acc[2]);
        acc[3] = fmaf(w, __uint_as_float(v.y & 0xffff0000u), acc[3]);
        acc[4] = fmaf(w, __uint_as_float(v.z << 16), acc[4]);
        acc[5] = fmaf(w, __uint_as_float(v.z & 0xffff0000u), acc[5]);
        acc[6] = fmaf(w, __uint_as_float(v.w << 16), acc[6]);
        acc[7] = fmaf(w, __uint_as_float(v.w & 0xffff0000u), acc[7]);
    };

    if (slot == 0) {
        uint4 v = *(const uint4*)&X[(size_t)wid * ldx + cg * 8];
        fma_row(v, di * di);
    }
    const int e0 = row_ptr[wid], e1 = row_ptr[wid + 1];
    int e = e0 + slot;
    for (; e + SLOTS < e1; e += 2 * SLOTS) {
        const int2 d0 = edge_data[e];
        const int2 d1 = edge_data[e + SLOTS];
        const uint4 v0 = *(const uint4*)&X[(size_t)d0.x * ldx + cg * 8];
        const uint4 v1 = *(const uint4*)&X[(size_t)d1.x * ldx + cg * 8];
        fma_row(v0, di * __int_as_float(d0.y));
        fma_row(v1, di * __int_as_float(d1.y));
    }
    if (e < e1) {
        const int2 d0 = edge_data[e];
        const uint4 v0 = *(const uint4*)&X[(size_t)d0.x * ldx + cg * 8];
        fma_row(v0, di * __int_as_float(d0.y));
    }
#pragma unroll
    for (int j = 0; j < 8; ++j) {
        if (SLOTS == 4) acc[j] += __shfl_xor(acc[j], 16);
        if (SLOTS >= 2) acc[j] += __shfl_xor(acc[j], 32);
    }
    if (slot == 0) {
        float* dst = &Y[(size_t)wid * ldy + cg * 8];
        *(float4*)&dst[0] = make_float4(acc[0], acc[1], acc[2], acc[3]);
        *(float4*)&dst[4] = make_float4(acc[4], acc[5], acc[6], acc[7]);
    }
}

// ---------------------------------------------------------------------------
// fp32 GEMM: Y[r, cb+c] = act( sum_k X[r,k]*W[k,c] + bias[c] )
// 64x64 block tile, 4x4 per thread, K chunked by 64 through LDS.
// obf16 != 0 -> Y is ushort* (bf16 RNE), else float*.
// ---------------------------------------------------------------------------
__global__ __launch_bounds__(256)
void gemm_kernel(const float* __restrict__ X, int ldx,
                 const float* __restrict__ W, int ldw,
                 const float* __restrict__ bias,
                 void* __restrict__ Yv, int ldy,
                 int nrows, int K, int relu, int obf16) {
    __shared__ float Xs[64][68];  // [k][row]
    __shared__ float Ws[64][68];  // [k][col]
    const int tid = threadIdx.x;
    const int tx = tid & 15;
    const int ty = tid >> 4;
    const int rb = blockIdx.x * 64;
    const int cb = blockIdx.y * 64;

    float acc[4][4] = {{0.f}};

    for (int k0 = 0; k0 < K; k0 += 64) {
#pragma unroll
        for (int q = 0; q < 4; ++q) {
            int idx = tid + q * 256;
            int row = idx >> 4;
            int kq  = idx & 15;
            float4 v = make_float4(0.f, 0.f, 0.f, 0.f);
            int r = rb + row;
            if (r < nrows) v = *(const float4*)&X[(size_t)r * ldx + k0 + kq * 4];
            Xs[kq * 4 + 0][row] = v.x;
            Xs[kq * 4 + 1][row] = v.y;
            Xs[kq * 4 + 2][row] = v.z;
            Xs[kq * 4 + 3][row] = v.w;
        }
#pragma unroll
        for (int q = 0; q < 4; ++q) {
            int idx = tid + q * 256;
            int k  = idx >> 4;
            int c4 = idx & 15;
            float4 v = *(const float4*)&W[(size_t)(k0 + k) * ldw + cb + c4 * 4];
            *(float4*)&Ws[k][c4 * 4] = v;
        }
        __syncthreads();
#pragma unroll 16
        for (int k = 0; k < 64; ++k) {
            const float4 xv = *(const float4*)&Xs[k][ty * 4];
            const float4 wv = *(const float4*)&Ws[k][tx * 4];
            const float xr[4] = {xv.x, xv.y, xv.z, xv.w};
            const float wr[4] = {wv.x, wv.y, wv.z, wv.w};
#pragma unroll
            for (int i = 0; i < 4; ++i)
#pragma unroll
                for (int j = 0; j < 4; ++j)
                    acc[i][j] = fmaf(xr[i], wr[j], acc[i][j]);
        }
        __syncthreads();
    }

    const float4 bv = *(const float4*)&bias[cb + tx * 4];
    const float br[4] = {bv.x, bv.y, bv.z, bv.w};
#pragma unroll
    for (int i = 0; i < 4; ++i) {
        int r = rb + ty * 4 + i;
        if (r >= nrows) continue;
        float v0 = acc[i][0] + br[0];
        float v1 = acc[i][1] + br[1];
        float v2 = acc[i][2] + br[2];
        float v3 = acc[i][3] + br[3];
        if (relu) {
            v0 = fmaxf(v0, 0.f); v1 = fmaxf(v1, 0.f);
            v2 = fmaxf(v2, 0.f); v3 = fmaxf(v3, 0.f);
        }
        if (obf16) {
            ushort4 o;
            o.x = f2bf(v0); o.y = f2bf(v1); o.z = f2bf(v2); o.w = f2bf(v3);
            *(ushort4*)&((ushort*)Yv)[(size_t)r * ldy + cb + tx * 4] = o;
        } else {
            *(float4*)&((float*)Yv)[(size_t)r * ldy + cb + tx * 4] = make_float4(v0, v1, v2, v3);
        }
    }
}

// ---------------------------------------------------------------------------
// Attention fusion: per node, 2-way softmax over (h1.Watt+b, h2.Watt+b).
// h1 is bf16 (cols 256:384 of cat1, ld=384), h2 is fp32.
// ---------------------------------------------------------------------------
__global__ __launch_bounds__(64)
void attn_kernel(const ushort* __restrict__ h1bf, const float* __restrict__ h2,
                 const float* __restrict__ Watt, const float* __restrict__ batt,
                 float* __restrict__ out, int ldout) {
    int i = blockIdx.x;
    int l = threadIdx.x;
    const ushort* h1p = &h1bf[(size_t)i * 384 + 256];
    float w0 = Watt[l], w1w = Watt[l + 64];
    float h1a = bf2f(h1p[l]),               h1b = bf2f(h1p[l + 64]);
    float h2a = h2[(size_t)i * 128 + l],    h2b = h2[(size_t)i * 128 + l + 64];
    float a = h1a * w0 + h1b * w1w;
    float b = h2a * w0 + h2b * w1w;
#pragma unroll
    for (int off = 32; off > 0; off >>= 1) {
        a += __shfl_xor(a, off);
        b += __shfl_xor(b, off);
    }
    float ba = batt[0];
    a += ba; b += ba;
    float m  = fmaxf(a, b);
    float ea = __expf(a - m), eb = __expf(b - m);
    float inv = 1.f / (ea + eb);
    float wa = ea * inv, wb = eb * inv;
    out[(size_t)i * ldout + l]      = wa * h1a + wb * h2a;
    out[(size_t)i * ldout + l + 64] = wa * h1b + wb * h2b;
}

// ---------------------------------------------------------------------------
extern "C" void kernel_launch(void* const* d_in, const int* in_sizes, int n_in,
                              void* d_out, int out_size, void* d_ws, size_t ws_size,
                              hipStream_t stream) {
    const int N = N_NODES, E = N_EDGES;
    const float* x     = (const float*)d_in[0];
    const int*   ei    = (const int*)d_in[1];
    const int*   esrc  = ei;
    const int*   edst  = ei + E;
    const float* W_s1  = (const float*)d_in[2];
    const float* b_s1  = (const float*)d_in[3];
    const float* W_s2  = (const float*)d_in[4];
    const float* b_s2  = (const float*)d_in[5];
    const float* W_m1  = (const float*)d_in[6];
    const float* b_m1  = (const float*)d_in[7];
    const float* W_m21 = (const float*)d_in[8];
    const float* b_m21 = (const float*)d_in[9];
    const float* W_m22 = (const float*)d_in[10];
    const float* b_m22 = (const float*)d_in[11];
    const float* W_att = (const float*)d_in[12];
    const float* b_att = (const float*)d_in[13];
    const float* W_fc  = (const float*)d_in[14];
    const float* b_fc  = (const float*)d_in[15];
    float* out = (float*)d_out;

    char* base = (char*)d_ws;
    size_t off = 0;
    auto take = [&](size_t nbytes) -> void* {
        void* p = base + off;
        off += (nbytes + 255) & ~(size_t)255;
        return p;
    };
    int*    hist      = (int*)take((size_t)N * 4);
    int*    cursor    = (int*)take((size_t)N * 4);
    int*    row_ptr   = (int*)take((size_t)(N + 1) * 4);
    int*    bsum      = (int*)take((size_t)SCAN_NB * 4);
    int*    bpre      = (int*)take((size_t)SCAN_NB * 4);
    int2*   edge_data = (int2*)take((size_t)E * 8);
    float*  dinv      = (float*)take((size_t)N * 4);
    ushort* xb        = (ushort*)take((size_t)N * 128 * 2);   // x in bf16
    float*  agg_x     = (float*)take((size_t)N * 128 * 4);    // S @ x (fp32)
    ushort* cat1      = (ushort*)take((size_t)N * 384 * 2);   // [h_s1 | h2a | h1] bf16
    float*  bufB      = (float*)take((size_t)N * 256 * 4);    // S @ cat1[:,0:256]
    float*  comb      = (float*)take((size_t)N * 256 * 4);    // [h_struct | h_meta]
    float*  h2buf     = (float*)take((size_t)N * 128 * 4);    // h2 fp32
    float*  Wcat      = (float*)take((size_t)128 * 384 * 4);
    float*  bcat      = (float*)take((size_t)384 * 4);

    // ---- CSR build + norms ----
    hipMemsetAsync(hist, 0, (size_t)N * 4, stream);
    degree_kernel<<<(E + 255) / 256, 256, 0, stream>>>(edst, E, hist);
    dinv_kernel<<<(N + 255) / 256, 256, 0, stream>>>(hist, dinv, N);
    scan1_kernel<<<SCAN_NB, SCAN_BS, 0, stream>>>(hist, bsum, N);
    scan2_kernel<<<1, SCAN_BS, 0, stream>>>(bsum, bpre, SCAN_NB, row_ptr, N);
    scan3_kernel<<<SCAN_NB, SCAN_BS, 0, stream>>>(hist, bpre, row_ptr, cursor, N);
    fill_kernel<<<(E + 255) / 256, 256, 0, stream>>>(esrc, edst, E, cursor, edge_data, dinv);

    // ---- prep: x -> bf16; pack fused layer-1 weights ----
    cvt_bf16_kernel<<<(N * 128 / 4 + 255) / 256, 256, 0, stream>>>(x, (uint2*)xb, N * 128 / 4);
    pack_w_kernel<<<(128 * 384 + 255) / 256, 256, 0, stream>>>(W_s1, W_m21, W_m1,
                                                               b_s1, b_m21, b_m1, Wcat, bcat);

    // ---- layer 1: one bf16 aggregation feeds one fused GEMM ----
    agg_bf16<128><<<(N + 3) / 4, 256, 0, stream>>>(xb, 128, agg_x, 128, row_ptr, edge_data, dinv, N);

    dim3 g384((N + 63) / 64, 6);
    dim3 g128((N + 63) / 64, 2);
    dim3 g64((N + 63) / 64, 1);
    // cat1 = relu(agg_x @ [W_s1|W_m21|W_m1] + bcat), bf16 out
    gemm_kernel<<<g384, 256, 0, stream>>>(agg_x, 128, Wcat, 384, bcat, cat1, 384, N, 128, 1, 1);

    // ---- layer 2: one 256-channel bf16 aggregation of [h_s1 | h2a] ----
    agg_bf16<256><<<(N + 3) / 4, 256, 0, stream>>>(cat1, 384, bufB, 256, row_ptr, edge_data, dinv, N);

    // h_struct -> comb[:, 0:128]
    gemm_kernel<<<g128, 256, 0, stream>>>(bufB, 256, W_s2, 128, b_s2, comb, 256, N, 128, 1, 0);
    // h2 -> h2buf
    gemm_kernel<<<g128, 256, 0, stream>>>(bufB + 128, 256, W_m22, 128, b_m22, h2buf, 128, N, 128, 1, 0);

    // ---- attention fusion: h_meta -> comb[:, 128:256] ----
    attn_kernel<<<N, 64, 0, stream>>>(cat1, h2buf, W_att, b_att, comb + 128, 256);

    // ---- final: out = comb @ W_fc + b_fc ----
    gemm_kernel<<<g64, 256, 0, stream>>>(comb, 256, W_fc, 64, b_fc, out, 64, N, 256, 0, 0);
}

// Round 5
// 423.676 us; speedup vs baseline: 1.7748x; 1.1586x over previous
//
#include <hip/hip_runtime.h>
#include <hip/hip_bf16.h>

#define N_NODES 50000
#define N_EDGES 800000
#define IN_C 128
#define HID_C 128
#define OUT_C 64

#define SCAN_BS 256
#define SCAN_NB ((N_NODES + SCAN_BS - 1) / SCAN_BS)   // 196

typedef __attribute__((ext_vector_type(8))) short bf16x8;
typedef __attribute__((ext_vector_type(4))) float f32x4;

__device__ __forceinline__ ushort f2bf(float f) {
    unsigned u = __float_as_uint(f);
    return (ushort)((u + 0x7fffu + ((u >> 16) & 1u)) >> 16);
}
__device__ __forceinline__ float bf2f(ushort u) {
    return __uint_as_float(((unsigned)u) << 16);
}

// ---------------------------------------------------------------------------
// CSR build: histogram of dst, 3-phase scan -> row_ptr, fill (src, dinv[src])
// ---------------------------------------------------------------------------
__global__ void degree_kernel(const int* __restrict__ dst, int E, int* __restrict__ hist) {
    int e = blockIdx.x * blockDim.x + threadIdx.x;
    if (e < E) atomicAdd(&hist[dst[e]], 1);
}

__global__ void dinv_kernel(const int* __restrict__ hist, float* __restrict__ dinv, int n) {
    int i = blockIdx.x * blockDim.x + threadIdx.x;
    if (i < n) dinv[i] = rsqrtf((float)(hist[i] + 1));  // +1 self loop
}

__global__ __launch_bounds__(SCAN_BS)
void scan1_kernel(const int* __restrict__ hist, int* __restrict__ bsum, int n) {
    __shared__ int s[SCAN_BS];
    int t = threadIdx.x;
    int i = blockIdx.x * SCAN_BS + t;
    int v = (i < n) ? hist[i] : 0;
    s[t] = v;
    __syncthreads();
#pragma unroll
    for (int off = SCAN_BS / 2; off > 0; off >>= 1) {
        if (t < off) s[t] += s[t + off];
        __syncthreads();
    }
    if (t == 0) bsum[blockIdx.x] = s[0];
}

__global__ __launch_bounds__(SCAN_BS)
void scan2_kernel(int* __restrict__ bsum, int* __restrict__ bpre, int nb,
                  int* __restrict__ row_ptr_last, int n) {
    __shared__ int s[SCAN_BS];
    int t = threadIdx.x;
    int v = (t < nb) ? bsum[t] : 0;
    s[t] = v;
    __syncthreads();
#pragma unroll
    for (int off = 1; off < SCAN_BS; off <<= 1) {
        int tmp = (t >= off) ? s[t - off] : 0;
        __syncthreads();
        s[t] += tmp;
        __syncthreads();
    }
    if (t < nb) bpre[t] = s[t] - v;
    if (t == SCAN_BS - 1) row_ptr_last[n] = s[t];
}

__global__ __launch_bounds__(SCAN_BS)
void scan3_kernel(const int* __restrict__ hist, const int* __restrict__ bpre,
                  int* __restrict__ row_ptr, int* __restrict__ cursor, int n) {
    __shared__ int s[SCAN_BS];
    int t = threadIdx.x;
    int i = blockIdx.x * SCAN_BS + t;
    int v = (i < n) ? hist[i] : 0;
    s[t] = v;
    __syncthreads();
#pragma unroll
    for (int off = 1; off < SCAN_BS; off <<= 1) {
        int tmp = (t >= off) ? s[t - off] : 0;
        __syncthreads();
        s[t] += tmp;
        __syncthreads();
    }
    if (i < n) {
        int ex = s[t] - v + bpre[blockIdx.x];
        row_ptr[i] = ex;
        cursor[i]  = ex;
    }
}

__global__ void fill_kernel(const int* __restrict__ src, const int* __restrict__ dst, int E,
                            int* __restrict__ cursor, int2* __restrict__ edge_data,
                            const float* __restrict__ dinv) {
    int e = blockIdx.x * blockDim.x + threadIdx.x;
    if (e < E) {
        int d = dst[e];
        int s = src[e];
        int pos = atomicAdd(&cursor[d], 1);
        edge_data[pos] = make_int2(s, __float_as_int(dinv[s]));
    }
}

// ---------------------------------------------------------------------------
// fp32 -> bf16 conversion (RNE), 4 floats -> 2 uints per thread
// ---------------------------------------------------------------------------
__global__ void cvt_bf16_kernel(const float* __restrict__ in, uint2* __restrict__ out, int n4) {
    int i = blockIdx.x * blockDim.x + threadIdx.x;
    if (i >= n4) return;
    float4 v = *(const float4*)&in[(size_t)i * 4];
    uint2 o;
    o.x = (uint)f2bf(v.x) | ((uint)f2bf(v.y) << 16);
    o.y = (uint)f2bf(v.z) | ((uint)f2bf(v.w) << 16);
    out[i] = o;
}

// ---------------------------------------------------------------------------
// Weight packing: transposed bf16 W^T[c][k] for MFMA B-fragment loads
// ---------------------------------------------------------------------------
__global__ void pack_wcat_kernel(const float* __restrict__ Ws1, const float* __restrict__ Wm21,
                                 const float* __restrict__ Wm1,
                                 const float* __restrict__ bs1, const float* __restrict__ bm21,
                                 const float* __restrict__ bm1,
                                 ushort* __restrict__ Wt, float* __restrict__ bcat) {
    int idx = blockIdx.x * blockDim.x + threadIdx.x;   // 384*128
    if (idx < 384 * 128) {
        int c = idx >> 7, k = idx & 127;
        float v = (c < 128) ? Ws1[k * 128 + c]
                : (c < 256) ? Wm21[k * 128 + (c - 128)]
                            : Wm1[k * 128 + (c - 256)];
        Wt[idx] = f2bf(v);
    }
    if (idx < 384) {
        bcat[idx] = (idx < 128) ? bs1[idx] : (idx < 256) ? bm21[idx - 128] : bm1[idx - 256];
    }
}

// generic K x C fp32 -> C x K bf16 transpose-pack (K=C=128 here)
__global__ void tpack_kernel(const float* __restrict__ W, ushort* __restrict__ Wt, int K, int C) {
    int idx = blockIdx.x * blockDim.x + threadIdx.x;
    if (idx >= K * C) return;
    int c = idx / K, k = idx % K;
    Wt[idx] = f2bf(W[(size_t)k * C + c]);
}

// ---------------------------------------------------------------------------
// bf16-gather aggregation, bf16 OUT (feeds MFMA GEMMs). One wave per node.
// ---------------------------------------------------------------------------
template<int C>
__global__ __launch_bounds__(256)
void agg_bf16(const ushort* __restrict__ X, int ldx,
              ushort* __restrict__ Y, int ldy,
              const int* __restrict__ row_ptr,
              const int2* __restrict__ edge_data,
              const float* __restrict__ dinv, int n) {
    constexpr int CG = C / 8;       // lanes per row
    constexpr int SLOTS = 64 / CG;  // 2 for C=256, 4 for C=128
    const int wid = blockIdx.x * (blockDim.x >> 6) + (threadIdx.x >> 6);
    if (wid >= n) return;
    const int lane = threadIdx.x & 63;
    const int cg = lane & (CG - 1);
    const int slot = lane / CG;

    const float di = dinv[wid];
    float acc[8] = {0.f, 0.f, 0.f, 0.f, 0.f, 0.f, 0.f, 0.f};

    auto fma_row = [&](uint4 v, float w) {
        acc[0] = fmaf(w, __uint_as_float(v.x << 16), acc[0]);
        acc[1] = fmaf(w, __uint_as_float(v.x & 0xffff0000u), acc[1]);
        acc[2] = fmaf(w, __uint_as_float(v.y << 16), acc[2]);
        acc[3] = fmaf(w, __uint_as_float(v.y & 0xffff0000u), acc[3]);
        acc[4] = fmaf(w, __uint_as_float(v.z << 16), acc[4]);
        acc[5] = fmaf(w, __uint_as_float(v.z & 0xffff0000u), acc[5]);
        acc[6] = fmaf(w, __uint_as_float(v.w << 16), acc[6]);
        acc[7] = fmaf(w, __uint_as_float(v.w & 0xffff0000u), acc[7]);
    };

    if (slot == 0) {
        uint4 v = *(const uint4*)&X[(size_t)wid * ldx + cg * 8];
        fma_row(v, di * di);
    }
    const int e0 = row_ptr[wid], e1 = row_ptr[wid + 1];
    int e = e0 + slot;
    for (; e + SLOTS < e1; e += 2 * SLOTS) {
        const int2 d0 = edge_data[e];
        const int2 d1 = edge_data[e + SLOTS];
        const uint4 v0 = *(const uint4*)&X[(size_t)d0.x * ldx + cg * 8];
        const uint4 v1 = *(const uint4*)&X[(size_t)d1.x * ldx + cg * 8];
        fma_row(v0, di * __int_as_float(d0.y));
        fma_row(v1, di * __int_as_float(d1.y));
    }
    if (e < e1) {
        const int2 d0 = edge_data[e];
        const uint4 v0 = *(const uint4*)&X[(size_t)d0.x * ldx + cg * 8];
        fma_row(v0, di * __int_as_float(d0.y));
    }
#pragma unroll
    for (int j = 0; j < 8; ++j) {
        if (SLOTS == 4) acc[j] += __shfl_xor(acc[j], 16);
        if (SLOTS >= 2) acc[j] += __shfl_xor(acc[j], 32);
    }
    if (slot == 0) {
        uint4 o;
        o.x = (uint)f2bf(acc[0]) | ((uint)f2bf(acc[1]) << 16);
        o.y = (uint)f2bf(acc[2]) | ((uint)f2bf(acc[3]) << 16);
        o.z = (uint)f2bf(acc[4]) | ((uint)f2bf(acc[5]) << 16);
        o.w = (uint)f2bf(acc[6]) | ((uint)f2bf(acc[7]) << 16);
        *(uint4*)&Y[(size_t)wid * ldy + cg * 8] = o;
    }
}

// ---------------------------------------------------------------------------
// bf16 MFMA GEMM, K=128 fixed. BM=128, BN=128, 256 threads (4 waves).
// A (bf16, row-major, lda) staged in LDS (row pad +16B -> conflict-free).
// B fragments read directly from global W^T[c][128] (L2-resident, shared
// across all blocks). C accumulated fp32; epilogue adds bias, optional relu,
// writes bf16 or fp32.
// ---------------------------------------------------------------------------
__global__ __launch_bounds__(256)
void mfma_gemm_kernel(const ushort* __restrict__ A, int lda,
                      const ushort* __restrict__ Wt,  // [C][128] bf16
                      const float* __restrict__ bias,
                      void* __restrict__ Yv, int ldy,
                      int M, int relu, int obf16) {
    __shared__ char Asmem[128 * 272];   // 128 rows x (256B data + 16B pad)
    const int tid = threadIdx.x;
    const int lane = tid & 63;
    const int w = tid >> 6;
    const int rb = blockIdx.x * 128;
    const int cb = blockIdx.y * 128;

    // stage A tile: 128 rows x 128 k (bf16), coalesced 16B per thread
    {
        const int rowbase = tid >> 4;          // 0..15
        const int inrow = (tid & 15) * 8;      // ushort offset within row
#pragma unroll
        for (int it = 0; it < 8; ++it) {
            int row = it * 16 + rowbase;
            uint4 v = make_uint4(0u, 0u, 0u, 0u);
            int r = rb + row;
            if (r < M) v = *(const uint4*)&A[(size_t)r * lda + inrow];
            *(uint4*)&Asmem[row * 272 + (tid & 15) * 16] = v;
        }
    }
    __syncthreads();

    f32x4 acc[2][8];
#pragma unroll
    for (int i = 0; i < 2; ++i)
#pragma unroll
        for (int j = 0; j < 8; ++j) acc[i][j] = (f32x4){0.f, 0.f, 0.f, 0.f};

    const int arow0 = w * 32 + (lane & 15);
    const int kq = (lane >> 4) * 8;
    const int ccol = lane & 15;
#pragma unroll
    for (int ks = 0; ks < 4; ++ks) {
        const int k0 = ks * 32;
        const bf16x8 a0 = *(const bf16x8*)&Asmem[arow0 * 272 + (k0 + kq) * 2];
        const bf16x8 a1 = *(const bf16x8*)&Asmem[(arow0 + 16) * 272 + (k0 + kq) * 2];
#pragma unroll
        for (int ct = 0; ct < 8; ++ct) {
            const bf16x8 b = *(const bf16x8*)&Wt[(size_t)(cb + ct * 16 + ccol) * 128 + k0 + kq];
            acc[0][ct] = __builtin_amdgcn_mfma_f32_16x16x32_bf16(a0, b, acc[0][ct], 0, 0, 0);
            acc[1][ct] = __builtin_amdgcn_mfma_f32_16x16x32_bf16(a1, b, acc[1][ct], 0, 0, 0);
        }
    }

    // epilogue: C layout col=lane&15, row=(lane>>4)*4+r
    const int rowq = (lane >> 4) * 4;
#pragma unroll
    for (int rt = 0; rt < 2; ++rt) {
#pragma unroll
        for (int ct = 0; ct < 8; ++ct) {
            const int col = cb + ct * 16 + ccol;
            const float bcol = bias[col];
#pragma unroll
            for (int r = 0; r < 4; ++r) {
                const int row = rb + w * 32 + rt * 16 + rowq + r;
                if (row >= M) continue;
                float v = acc[rt][ct][r] + bcol;
                if (relu) v = fmaxf(v, 0.f);
                if (obf16) ((ushort*)Yv)[(size_t)row * ldy + col] = f2bf(v);
                else       ((float*)Yv)[(size_t)row * ldy + col] = v;
            }
        }
    }
}

// ---------------------------------------------------------------------------
// fp32 GEMM (kept for the final fc layer: K=256, 64 cols, memory-bound)
// ---------------------------------------------------------------------------
__global__ __launch_bounds__(256)
void gemm_kernel(const float* __restrict__ X, int ldx,
                 const float* __restrict__ W, int ldw,
                 const float* __restrict__ bias,
                 void* __restrict__ Yv, int ldy,
                 int nrows, int K, int relu, int obf16) {
    __shared__ float Xs[64][68];
    __shared__ float Ws[64][68];
    const int tid = threadIdx.x;
    const int tx = tid & 15;
    const int ty = tid >> 4;
    const int rb = blockIdx.x * 64;
    const int cb = blockIdx.y * 64;

    float acc[4][4] = {{0.f}};

    for (int k0 = 0; k0 < K; k0 += 64) {
#pragma unroll
        for (int q = 0; q < 4; ++q) {
            int idx = tid + q * 256;
            int row = idx >> 4;
            int kq  = idx & 15;
            float4 v = make_float4(0.f, 0.f, 0.f, 0.f);
            int r = rb + row;
            if (r < nrows) v = *(const float4*)&X[(size_t)r * ldx + k0 + kq * 4];
            Xs[kq * 4 + 0][row] = v.x;
            Xs[kq * 4 + 1][row] = v.y;
            Xs[kq * 4 + 2][row] = v.z;
            Xs[kq * 4 + 3][row] = v.w;
        }
#pragma unroll
        for (int q = 0; q < 4; ++q) {
            int idx = tid + q * 256;
            int k  = idx >> 4;
            int c4 = idx & 15;
            float4 v = *(const float4*)&W[(size_t)(k0 + k) * ldw + cb + c4 * 4];
            *(float4*)&Ws[k][c4 * 4] = v;
        }
        __syncthreads();
#pragma unroll 16
        for (int k = 0; k < 64; ++k) {
            const float4 xv = *(const float4*)&Xs[k][ty * 4];
            const float4 wv = *(const float4*)&Ws[k][tx * 4];
            const float xr[4] = {xv.x, xv.y, xv.z, xv.w};
            const float wr[4] = {wv.x, wv.y, wv.z, wv.w};
#pragma unroll
            for (int i = 0; i < 4; ++i)
#pragma unroll
                for (int j = 0; j < 4; ++j)
                    acc[i][j] = fmaf(xr[i], wr[j], acc[i][j]);
        }
        __syncthreads();
    }

    const float4 bv = *(const float4*)&bias[cb + tx * 4];
    const float br[4] = {bv.x, bv.y, bv.z, bv.w};
#pragma unroll
    for (int i = 0; i < 4; ++i) {
        int r = rb + ty * 4 + i;
        if (r >= nrows) continue;
        float v0 = acc[i][0] + br[0];
        float v1 = acc[i][1] + br[1];
        float v2 = acc[i][2] + br[2];
        float v3 = acc[i][3] + br[3];
        if (relu) {
            v0 = fmaxf(v0, 0.f); v1 = fmaxf(v1, 0.f);
            v2 = fmaxf(v2, 0.f); v3 = fmaxf(v3, 0.f);
        }
        if (obf16) {
            ushort4 o;
            o.x = f2bf(v0); o.y = f2bf(v1); o.z = f2bf(v2); o.w = f2bf(v3);
            *(ushort4*)&((ushort*)Yv)[(size_t)r * ldy + cb + tx * 4] = o;
        } else {
            *(float4*)&((float*)Yv)[(size_t)r * ldy + cb + tx * 4] = make_float4(v0, v1, v2, v3);
        }
    }
}

// ---------------------------------------------------------------------------
// Attention fusion: per node, 2-way softmax over (h1.Watt+b, h2.Watt+b).
// h1 is bf16 (cols 256:384 of cat1, ld=384), h2 is fp32.
// ---------------------------------------------------------------------------
__global__ __launch_bounds__(64)
void attn_kernel(const ushort* __restrict__ h1bf, const float* __restrict__ h2,
                 const float* __restrict__ Watt, const float* __restrict__ batt,
                 float* __restrict__ out, int ldout) {
    int i = blockIdx.x;
    int l = threadIdx.x;
    const ushort* h1p = &h1bf[(size_t)i * 384 + 256];
    float w0 = Watt[l], w1w = Watt[l + 64];
    float h1a = bf2f(h1p[l]),               h1b = bf2f(h1p[l + 64]);
    float h2a = h2[(size_t)i * 128 + l],    h2b = h2[(size_t)i * 128 + l + 64];
    float a = h1a * w0 + h1b * w1w;
    float b = h2a * w0 + h2b * w1w;
#pragma unroll
    for (int off = 32; off > 0; off >>= 1) {
        a += __shfl_xor(a, off);
        b += __shfl_xor(b, off);
    }
    float ba = batt[0];
    a += ba; b += ba;
    float m  = fmaxf(a, b);
    float ea = __expf(a - m), eb = __expf(b - m);
    float inv = 1.f / (ea + eb);
    float wa = ea * inv, wb = eb * inv;
    out[(size_t)i * ldout + l]      = wa * h1a + wb * h2a;
    out[(size_t)i * ldout + l + 64] = wa * h1b + wb * h2b;
}

// ---------------------------------------------------------------------------
extern "C" void kernel_launch(void* const* d_in, const int* in_sizes, int n_in,
                              void* d_out, int out_size, void* d_ws, size_t ws_size,
                              hipStream_t stream) {
    const int N = N_NODES, E = N_EDGES;
    const float* x     = (const float*)d_in[0];
    const int*   ei    = (const int*)d_in[1];
    const int*   esrc  = ei;
    const int*   edst  = ei + E;
    const float* W_s1  = (const float*)d_in[2];
    const float* b_s1  = (const float*)d_in[3];
    const float* W_s2  = (const float*)d_in[4];
    const float* b_s2  = (const float*)d_in[5];
    const float* W_m1  = (const float*)d_in[6];
    const float* b_m1  = (const float*)d_in[7];
    const float* W_m21 = (const float*)d_in[8];
    const float* b_m21 = (const float*)d_in[9];
    const float* W_m22 = (const float*)d_in[10];
    const float* b_m22 = (const float*)d_in[11];
    const float* W_att = (const float*)d_in[12];
    const float* b_att = (const float*)d_in[13];
    const float* W_fc  = (const float*)d_in[14];
    const float* b_fc  = (const float*)d_in[15];
    float* out = (float*)d_out;

    char* base = (char*)d_ws;
    size_t off = 0;
    auto take = [&](size_t nbytes) -> void* {
        void* p = base + off;
        off += (nbytes + 255) & ~(size_t)255;
        return p;
    };
    int*    hist      = (int*)take((size_t)N * 4);
    int*    cursor    = (int*)take((size_t)N * 4);
    int*    row_ptr   = (int*)take((size_t)(N + 1) * 4);
    int*    bsum      = (int*)take((size_t)SCAN_NB * 4);
    int*    bpre      = (int*)take((size_t)SCAN_NB * 4);
    int2*   edge_data = (int2*)take((size_t)E * 8);
    float*  dinv      = (float*)take((size_t)N * 4);
    ushort* xb        = (ushort*)take((size_t)N * 128 * 2);   // x bf16
    ushort* agg_x     = (ushort*)take((size_t)N * 128 * 2);   // S @ x, bf16
    ushort* cat1      = (ushort*)take((size_t)N * 384 * 2);   // [h_s1 | h2a | h1] bf16
    ushort* bufB      = (ushort*)take((size_t)N * 256 * 2);   // S @ cat1[:,0:256], bf16
    float*  comb      = (float*)take((size_t)N * 256 * 4);    // [h_struct | h_meta] fp32
    float*  h2buf     = (float*)take((size_t)N * 128 * 4);    // h2 fp32
    ushort* Wcat_t    = (ushort*)take((size_t)384 * 128 * 2); // [c][k] bf16
    ushort* Ws2_t     = (ushort*)take((size_t)128 * 128 * 2);
    ushort* Wm22_t    = (ushort*)take((size_t)128 * 128 * 2);
    float*  bcat      = (float*)take((size_t)384 * 4);

    // ---- CSR build + norms ----
    hipMemsetAsync(hist, 0, (size_t)N * 4, stream);
    degree_kernel<<<(E + 255) / 256, 256, 0, stream>>>(edst, E, hist);
    dinv_kernel<<<(N + 255) / 256, 256, 0, stream>>>(hist, dinv, N);
    scan1_kernel<<<SCAN_NB, SCAN_BS, 0, stream>>>(hist, bsum, N);
    scan2_kernel<<<1, SCAN_BS, 0, stream>>>(bsum, bpre, SCAN_NB, row_ptr, N);
    scan3_kernel<<<SCAN_NB, SCAN_BS, 0, stream>>>(hist, bpre, row_ptr, cursor, N);
    fill_kernel<<<(E + 255) / 256, 256, 0, stream>>>(esrc, edst, E, cursor, edge_data, dinv);

    // ---- prep: x -> bf16; pack transposed bf16 weights ----
    cvt_bf16_kernel<<<(N * 128 / 4 + 255) / 256, 256, 0, stream>>>(x, (uint2*)xb, N * 128 / 4);
    pack_wcat_kernel<<<(384 * 128 + 255) / 256, 256, 0, stream>>>(W_s1, W_m21, W_m1,
                                                                  b_s1, b_m21, b_m1, Wcat_t, bcat);
    tpack_kernel<<<(128 * 128 + 255) / 256, 256, 0, stream>>>(W_s2, Ws2_t, 128, 128);
    tpack_kernel<<<(128 * 128 + 255) / 256, 256, 0, stream>>>(W_m22, Wm22_t, 128, 128);

    // ---- layer 1: one bf16 aggregation feeds one fused MFMA GEMM ----
    agg_bf16<128><<<(N + 3) / 4, 256, 0, stream>>>(xb, 128, agg_x, 128, row_ptr, edge_data, dinv, N);

    dim3 gm384((N + 127) / 128, 3);
    dim3 gm128((N + 127) / 128, 1);
    // cat1 = relu(agg_x @ [W_s1|W_m21|W_m1] + bcat), bf16 out
    mfma_gemm_kernel<<<gm384, 256, 0, stream>>>(agg_x, 128, Wcat_t, bcat, cat1, 384, N, 1, 1);

    // ---- layer 2: one 256-channel bf16 aggregation of [h_s1 | h2a] ----
    agg_bf16<256><<<(N + 3) / 4, 256, 0, stream>>>(cat1, 384, bufB, 256, row_ptr, edge_data, dinv, N);

    // h_struct -> comb[:, 0:128] (fp32 out)
    mfma_gemm_kernel<<<gm128, 256, 0, stream>>>(bufB, 256, Ws2_t, b_s2, comb, 256, N, 1, 0);
    // h2 -> h2buf (fp32 out)
    mfma_gemm_kernel<<<gm128, 256, 0, stream>>>(bufB + 128, 256, Wm22_t, b_m22, h2buf, 128, N, 1, 0);

    // ---- attention fusion: h_meta -> comb[:, 128:256] ----
    attn_kernel<<<N, 64, 0, stream>>>(cat1, h2buf, W_att, b_att, comb + 128, 256);

    // ---- final: out = comb @ W_fc + b_fc (fp32, memory-bound) ----
    dim3 g64((N + 63) / 64, 1);
    gemm_kernel<<<g64, 256, 0, stream>>>(comb, 256, W_fc, 64, b_fc, out, 64, N, 256, 0, 0);
}

// Round 6
// 414.041 us; speedup vs baseline: 1.8161x; 1.0233x over previous
//
#include <hip/hip_runtime.h>
#include <hip/hip_bf16.h>

#define N_NODES 50000
#define N_EDGES 800000
#define IN_C 128
#define HID_C 128
#define OUT_C 64

#define SCAN_BS 256
#define SCAN_NB ((N_NODES + SCAN_BS - 1) / SCAN_BS)   // 196

typedef __attribute__((ext_vector_type(8))) short bf16x8;
typedef __attribute__((ext_vector_type(4))) float f32x4;

__device__ __forceinline__ ushort f2bf(float f) {
    unsigned u = __float_as_uint(f);
    return (ushort)((u + 0x7fffu + ((u >> 16) & 1u)) >> 16);
}
__device__ __forceinline__ float bf2f(ushort u) {
    return __uint_as_float(((unsigned)u) << 16);
}

// ---------------------------------------------------------------------------
// CSR build: histogram of dst, 3-phase scan -> row_ptr, fill (src, dinv[src])
// ---------------------------------------------------------------------------
__global__ void degree_kernel(const int* __restrict__ dst, int E, int* __restrict__ hist) {
    int e = blockIdx.x * blockDim.x + threadIdx.x;
    if (e < E) atomicAdd(&hist[dst[e]], 1);
}

__global__ void dinv_kernel(const int* __restrict__ hist, float* __restrict__ dinv, int n) {
    int i = blockIdx.x * blockDim.x + threadIdx.x;
    if (i < n) dinv[i] = rsqrtf((float)(hist[i] + 1));  // +1 self loop
}

__global__ __launch_bounds__(SCAN_BS)
void scan1_kernel(const int* __restrict__ hist, int* __restrict__ bsum, int n) {
    __shared__ int s[SCAN_BS];
    int t = threadIdx.x;
    int i = blockIdx.x * SCAN_BS + t;
    int v = (i < n) ? hist[i] : 0;
    s[t] = v;
    __syncthreads();
#pragma unroll
    for (int off = SCAN_BS / 2; off > 0; off >>= 1) {
        if (t < off) s[t] += s[t + off];
        __syncthreads();
    }
    if (t == 0) bsum[blockIdx.x] = s[0];
}

__global__ __launch_bounds__(SCAN_BS)
void scan2_kernel(int* __restrict__ bsum, int* __restrict__ bpre, int nb,
                  int* __restrict__ row_ptr_last, int n) {
    __shared__ int s[SCAN_BS];
    int t = threadIdx.x;
    int v = (t < nb) ? bsum[t] : 0;
    s[t] = v;
    __syncthreads();
#pragma unroll
    for (int off = 1; off < SCAN_BS; off <<= 1) {
        int tmp = (t >= off) ? s[t - off] : 0;
        __syncthreads();
        s[t] += tmp;
        __syncthreads();
    }
    if (t < nb) bpre[t] = s[t] - v;
    if (t == SCAN_BS - 1) row_ptr_last[n] = s[t];
}

__global__ __launch_bounds__(SCAN_BS)
void scan3_kernel(const int* __restrict__ hist, const int* __restrict__ bpre,
                  int* __restrict__ row_ptr, int* __restrict__ cursor, int n) {
    __shared__ int s[SCAN_BS];
    int t = threadIdx.x;
    int i = blockIdx.x * SCAN_BS + t;
    int v = (i < n) ? hist[i] : 0;
    s[t] = v;
    __syncthreads();
#pragma unroll
    for (int off = 1; off < SCAN_BS; off <<= 1) {
        int tmp = (t >= off) ? s[t - off] : 0;
        __syncthreads();
        s[t] += tmp;
        __syncthreads();
    }
    if (i < n) {
        int ex = s[t] - v + bpre[blockIdx.x];
        row_ptr[i] = ex;
        cursor[i]  = ex;
    }
}

__global__ void fill_kernel(const int* __restrict__ src, const int* __restrict__ dst, int E,
                            int* __restrict__ cursor, int2* __restrict__ edge_data,
                            const float* __restrict__ dinv) {
    int e = blockIdx.x * blockDim.x + threadIdx.x;
    if (e < E) {
        int d = dst[e];
        int s = src[e];
        int pos = atomicAdd(&cursor[d], 1);
        edge_data[pos] = make_int2(s, __float_as_int(dinv[s]));
    }
}

// ---------------------------------------------------------------------------
// fp32 -> bf16 conversion (RNE), 4 floats -> 2 uints per thread
// ---------------------------------------------------------------------------
__global__ void cvt_bf16_kernel(const float* __restrict__ in, uint2* __restrict__ out, int n4) {
    int i = blockIdx.x * blockDim.x + threadIdx.x;
    if (i >= n4) return;
    float4 v = *(const float4*)&in[(size_t)i * 4];
    uint2 o;
    o.x = (uint)f2bf(v.x) | ((uint)f2bf(v.y) << 16);
    o.y = (uint)f2bf(v.z) | ((uint)f2bf(v.w) << 16);
    out[i] = o;
}

// ---------------------------------------------------------------------------
// Weight packing: transposed bf16 W^T[c][k] for MFMA B-fragment loads
// ---------------------------------------------------------------------------
__global__ void pack_wcat_kernel(const float* __restrict__ Ws1, const float* __restrict__ Wm21,
                                 const float* __restrict__ Wm1,
                                 const float* __restrict__ bs1, const float* __restrict__ bm21,
                                 const float* __restrict__ bm1,
                                 ushort* __restrict__ Wt, float* __restrict__ bcat) {
    int idx = blockIdx.x * blockDim.x + threadIdx.x;   // 384*128
    if (idx < 384 * 128) {
        int c = idx >> 7, k = idx & 127;
        float v = (c < 128) ? Ws1[k * 128 + c]
                : (c < 256) ? Wm21[k * 128 + (c - 128)]
                            : Wm1[k * 128 + (c - 256)];
        Wt[idx] = f2bf(v);
    }
    if (idx < 384) {
        bcat[idx] = (idx < 128) ? bs1[idx] : (idx < 256) ? bm21[idx - 128] : bm1[idx - 256];
    }
}

// generic K x C fp32 -> C x K bf16 transpose-pack
__global__ void tpack_kernel(const float* __restrict__ W, ushort* __restrict__ Wt, int K, int C) {
    int idx = blockIdx.x * blockDim.x + threadIdx.x;
    if (idx >= K * C) return;
    int c = idx / K, k = idx % K;
    Wt[idx] = f2bf(W[(size_t)k * C + c]);
}

// ---------------------------------------------------------------------------
// bf16-gather aggregation, bf16 OUT. One wave per node, 4x unrolled edge loop
// (4 gather rows in flight per slot).
// ---------------------------------------------------------------------------
template<int C>
__global__ __launch_bounds__(256)
void agg_bf16(const ushort* __restrict__ X, int ldx,
              ushort* __restrict__ Y, int ldy,
              const int* __restrict__ row_ptr,
              const int2* __restrict__ edge_data,
              const float* __restrict__ dinv, int n) {
    constexpr int CG = C / 8;       // lanes per row
    constexpr int SLOTS = 64 / CG;  // 2 for C=256, 4 for C=128
    const int wid = blockIdx.x * (blockDim.x >> 6) + (threadIdx.x >> 6);
    if (wid >= n) return;
    const int lane = threadIdx.x & 63;
    const int cg = lane & (CG - 1);
    const int slot = lane / CG;

    const float di = dinv[wid];
    float acc[8] = {0.f, 0.f, 0.f, 0.f, 0.f, 0.f, 0.f, 0.f};

    auto fma_row = [&](uint4 v, float w) {
        acc[0] = fmaf(w, __uint_as_float(v.x << 16), acc[0]);
        acc[1] = fmaf(w, __uint_as_float(v.x & 0xffff0000u), acc[1]);
        acc[2] = fmaf(w, __uint_as_float(v.y << 16), acc[2]);
        acc[3] = fmaf(w, __uint_as_float(v.y & 0xffff0000u), acc[3]);
        acc[4] = fmaf(w, __uint_as_float(v.z << 16), acc[4]);
        acc[5] = fmaf(w, __uint_as_float(v.z & 0xffff0000u), acc[5]);
        acc[6] = fmaf(w, __uint_as_float(v.w << 16), acc[6]);
        acc[7] = fmaf(w, __uint_as_float(v.w & 0xffff0000u), acc[7]);
    };

    if (slot == 0) {
        uint4 v = *(const uint4*)&X[(size_t)wid * ldx + cg * 8];
        fma_row(v, di * di);
    }
    const int e0 = row_ptr[wid], e1 = row_ptr[wid + 1];
    int e = e0 + slot;
    for (; e + 3 * SLOTS < e1; e += 4 * SLOTS) {
        const int2 d0 = edge_data[e];
        const int2 d1 = edge_data[e + SLOTS];
        const int2 d2 = edge_data[e + 2 * SLOTS];
        const int2 d3 = edge_data[e + 3 * SLOTS];
        const uint4 v0 = *(const uint4*)&X[(size_t)d0.x * ldx + cg * 8];
        const uint4 v1 = *(const uint4*)&X[(size_t)d1.x * ldx + cg * 8];
        const uint4 v2 = *(const uint4*)&X[(size_t)d2.x * ldx + cg * 8];
        const uint4 v3 = *(const uint4*)&X[(size_t)d3.x * ldx + cg * 8];
        fma_row(v0, di * __int_as_float(d0.y));
        fma_row(v1, di * __int_as_float(d1.y));
        fma_row(v2, di * __int_as_float(d2.y));
        fma_row(v3, di * __int_as_float(d3.y));
    }
    for (; e < e1; e += SLOTS) {
        const int2 d0 = edge_data[e];
        const uint4 v0 = *(const uint4*)&X[(size_t)d0.x * ldx + cg * 8];
        fma_row(v0, di * __int_as_float(d0.y));
    }
#pragma unroll
    for (int j = 0; j < 8; ++j) {
        if (SLOTS == 4) acc[j] += __shfl_xor(acc[j], 16);
        if (SLOTS >= 2) acc[j] += __shfl_xor(acc[j], 32);
    }
    if (slot == 0) {
        uint4 o;
        o.x = (uint)f2bf(acc[0]) | ((uint)f2bf(acc[1]) << 16);
        o.y = (uint)f2bf(acc[2]) | ((uint)f2bf(acc[3]) << 16);
        o.z = (uint)f2bf(acc[4]) | ((uint)f2bf(acc[5]) << 16);
        o.w = (uint)f2bf(acc[6]) | ((uint)f2bf(acc[7]) << 16);
        *(uint4*)&Y[(size_t)wid * ldy + cg * 8] = o;
    }
}

// ---------------------------------------------------------------------------
// bf16 MFMA GEMM, K=128 fixed. BM=128, BN=128, 256 threads (4 waves).
// ---------------------------------------------------------------------------
__global__ __launch_bounds__(256)
void mfma_gemm_kernel(const ushort* __restrict__ A, int lda,
                      const ushort* __restrict__ Wt,  // [C][128] bf16
                      const float* __restrict__ bias,
                      void* __restrict__ Yv, int ldy,
                      int M, int relu, int obf16) {
    __shared__ char Asmem[128 * 272];   // 128 rows x (256B data + 16B pad)
    const int tid = threadIdx.x;
    const int lane = tid & 63;
    const int w = tid >> 6;
    const int rb = blockIdx.x * 128;
    const int cb = blockIdx.y * 128;

    {
        const int rowbase = tid >> 4;
        const int inrow = (tid & 15) * 8;
#pragma unroll
        for (int it = 0; it < 8; ++it) {
            int row = it * 16 + rowbase;
            uint4 v = make_uint4(0u, 0u, 0u, 0u);
            int r = rb + row;
            if (r < M) v = *(const uint4*)&A[(size_t)r * lda + inrow];
            *(uint4*)&Asmem[row * 272 + (tid & 15) * 16] = v;
        }
    }
    __syncthreads();

    f32x4 acc[2][8];
#pragma unroll
    for (int i = 0; i < 2; ++i)
#pragma unroll
        for (int j = 0; j < 8; ++j) acc[i][j] = (f32x4){0.f, 0.f, 0.f, 0.f};

    const int arow0 = w * 32 + (lane & 15);
    const int kq = (lane >> 4) * 8;
    const int ccol = lane & 15;
#pragma unroll
    for (int ks = 0; ks < 4; ++ks) {
        const int k0 = ks * 32;
        const bf16x8 a0 = *(const bf16x8*)&Asmem[arow0 * 272 + (k0 + kq) * 2];
        const bf16x8 a1 = *(const bf16x8*)&Asmem[(arow0 + 16) * 272 + (k0 + kq) * 2];
#pragma unroll
        for (int ct = 0; ct < 8; ++ct) {
            const bf16x8 b = *(const bf16x8*)&Wt[(size_t)(cb + ct * 16 + ccol) * 128 + k0 + kq];
            acc[0][ct] = __builtin_amdgcn_mfma_f32_16x16x32_bf16(a0, b, acc[0][ct], 0, 0, 0);
            acc[1][ct] = __builtin_amdgcn_mfma_f32_16x16x32_bf16(a1, b, acc[1][ct], 0, 0, 0);
        }
    }

    const int rowq = (lane >> 4) * 4;
#pragma unroll
    for (int rt = 0; rt < 2; ++rt) {
#pragma unroll
        for (int ct = 0; ct < 8; ++ct) {
            const int col = cb + ct * 16 + ccol;
            const float bcol = bias[col];
#pragma unroll
            for (int r = 0; r < 4; ++r) {
                const int row = rb + w * 32 + rt * 16 + rowq + r;
                if (row >= M) continue;
                float v = acc[rt][ct][r] + bcol;
                if (relu) v = fmaxf(v, 0.f);
                if (obf16) ((ushort*)Yv)[(size_t)row * ldy + col] = f2bf(v);
                else       ((float*)Yv)[(size_t)row * ldy + col] = v;
            }
        }
    }
}

// ---------------------------------------------------------------------------
// bf16 MFMA fc GEMM: K=256, N=64 fixed. BM=64, 256 threads (4 waves, each
// wave 16 rows x 64 cols). A = comb bf16 (ld 256), Wt [64][256] bf16.
// fp32 output (d_out).
// ---------------------------------------------------------------------------
__global__ __launch_bounds__(256)
void mfma_fc_kernel(const ushort* __restrict__ A,
                    const ushort* __restrict__ Wt,
                    const float* __restrict__ bias,
                    float* __restrict__ Y, int M) {
    __shared__ char Asmem[64 * 528];   // 64 rows x (512B data + 16B pad)
    const int tid = threadIdx.x;
    const int lane = tid & 63;
    const int w = tid >> 6;
    const int rb = blockIdx.x * 64;

    {
        const int rowbase = tid >> 5;       // 0..7
        const int seg = (tid & 31);         // 16B segment within 512B row
#pragma unroll
        for (int it = 0; it < 8; ++it) {
            int row = it * 8 + rowbase;
            uint4 v = make_uint4(0u, 0u, 0u, 0u);
            int r = rb + row;
            if (r < M) v = *(const uint4*)&A[(size_t)r * 256 + seg * 8];
            *(uint4*)&Asmem[row * 528 + seg * 16] = v;
        }
    }
    __syncthreads();

    f32x4 acc[4];
#pragma unroll
    for (int j = 0; j < 4; ++j) acc[j] = (f32x4){0.f, 0.f, 0.f, 0.f};

    const int arow = w * 16 + (lane & 15);
    const int kq = (lane >> 4) * 8;
    const int ccol = lane & 15;
#pragma unroll
    for (int ks = 0; ks < 8; ++ks) {
        const int k0 = ks * 32;
        const bf16x8 a = *(const bf16x8*)&Asmem[arow * 528 + (k0 + kq) * 2];
#pragma unroll
        for (int ct = 0; ct < 4; ++ct) {
            const bf16x8 b = *(const bf16x8*)&Wt[(size_t)(ct * 16 + ccol) * 256 + k0 + kq];
            acc[ct] = __builtin_amdgcn_mfma_f32_16x16x32_bf16(a, b, acc[ct], 0, 0, 0);
        }
    }

    const int rowq = (lane >> 4) * 4;
#pragma unroll
    for (int ct = 0; ct < 4; ++ct) {
        const int col = ct * 16 + ccol;
        const float bcol = bias[col];
#pragma unroll
        for (int r = 0; r < 4; ++r) {
            const int row = rb + w * 16 + rowq + r;
            if (row < M) Y[(size_t)row * 64 + col] = acc[ct][r] + bcol;
        }
    }
}

// ---------------------------------------------------------------------------
// Attention fusion: per node, 2-way softmax over (h1.Watt+b, h2.Watt+b).
// h1 bf16 (cols 256:384 of cat1, ld 384), h2 bf16 (ld 128), out bf16 (ld 256).
// ---------------------------------------------------------------------------
__global__ __launch_bounds__(64)
void attn_kernel(const ushort* __restrict__ h1bf, const ushort* __restrict__ h2bf,
                 const float* __restrict__ Watt, const float* __restrict__ batt,
                 ushort* __restrict__ outb, int ldout) {
    int i = blockIdx.x;
    int l = threadIdx.x;
    const ushort* h1p = &h1bf[(size_t)i * 384 + 256];
    const ushort* h2p = &h2bf[(size_t)i * 128];
    float w0 = Watt[l], w1w = Watt[l + 64];
    float h1a = bf2f(h1p[l]), h1b = bf2f(h1p[l + 64]);
    float h2a = bf2f(h2p[l]), h2b = bf2f(h2p[l + 64]);
    float a = h1a * w0 + h1b * w1w;
    float b = h2a * w0 + h2b * w1w;
#pragma unroll
    for (int off = 32; off > 0; off >>= 1) {
        a += __shfl_xor(a, off);
        b += __shfl_xor(b, off);
    }
    float ba = batt[0];
    a += ba; b += ba;
    float m  = fmaxf(a, b);
    float ea = __expf(a - m), eb = __expf(b - m);
    float inv = 1.f / (ea + eb);
    float wa = ea * inv, wb = eb * inv;
    outb[(size_t)i * ldout + l]      = f2bf(wa * h1a + wb * h2a);
    outb[(size_t)i * ldout + l + 64] = f2bf(wa * h1b + wb * h2b);
}

// ---------------------------------------------------------------------------
extern "C" void kernel_launch(void* const* d_in, const int* in_sizes, int n_in,
                              void* d_out, int out_size, void* d_ws, size_t ws_size,
                              hipStream_t stream) {
    const int N = N_NODES, E = N_EDGES;
    const float* x     = (const float*)d_in[0];
    const int*   ei    = (const int*)d_in[1];
    const int*   esrc  = ei;
    const int*   edst  = ei + E;
    const float* W_s1  = (const float*)d_in[2];
    const float* b_s1  = (const float*)d_in[3];
    const float* W_s2  = (const float*)d_in[4];
    const float* b_s2  = (const float*)d_in[5];
    const float* W_m1  = (const float*)d_in[6];
    const float* b_m1  = (const float*)d_in[7];
    const float* W_m21 = (const float*)d_in[8];
    const float* b_m21 = (const float*)d_in[9];
    const float* W_m22 = (const float*)d_in[10];
    const float* b_m22 = (const float*)d_in[11];
    const float* W_att = (const float*)d_in[12];
    const float* b_att = (const float*)d_in[13];
    const float* W_fc  = (const float*)d_in[14];
    const float* b_fc  = (const float*)d_in[15];
    float* out = (float*)d_out;

    char* base = (char*)d_ws;
    size_t off = 0;
    auto take = [&](size_t nbytes) -> void* {
        void* p = base + off;
        off += (nbytes + 255) & ~(size_t)255;
        return p;
    };
    int*    hist      = (int*)take((size_t)N * 4);
    int*    cursor    = (int*)take((size_t)N * 4);
    int*    row_ptr   = (int*)take((size_t)(N + 1) * 4);
    int*    bsum      = (int*)take((size_t)SCAN_NB * 4);
    int*    bpre      = (int*)take((size_t)SCAN_NB * 4);
    int2*   edge_data = (int2*)take((size_t)E * 8);
    float*  dinv      = (float*)take((size_t)N * 4);
    ushort* xb        = (ushort*)take((size_t)N * 128 * 2);   // x bf16
    ushort* agg_x     = (ushort*)take((size_t)N * 128 * 2);   // S @ x, bf16
    ushort* cat1      = (ushort*)take((size_t)N * 384 * 2);   // [h_s1 | h2a | h1] bf16
    ushort* bufB      = (ushort*)take((size_t)N * 256 * 2);   // S @ cat1[:,0:256], bf16
    ushort* comb      = (ushort*)take((size_t)N * 256 * 2);   // [h_struct | h_meta] bf16
    ushort* h2buf     = (ushort*)take((size_t)N * 128 * 2);   // h2 bf16
    ushort* Wcat_t    = (ushort*)take((size_t)384 * 128 * 2); // [c][k] bf16
    ushort* Ws2_t     = (ushort*)take((size_t)128 * 128 * 2);
    ushort* Wm22_t    = (ushort*)take((size_t)128 * 128 * 2);
    ushort* Wfc_t     = (ushort*)take((size_t)64 * 256 * 2);
    float*  bcat      = (float*)take((size_t)384 * 4);

    // ---- CSR build + norms ----
    hipMemsetAsync(hist, 0, (size_t)N * 4, stream);
    degree_kernel<<<(E + 255) / 256, 256, 0, stream>>>(edst, E, hist);
    dinv_kernel<<<(N + 255) / 256, 256, 0, stream>>>(hist, dinv, N);
    scan1_kernel<<<SCAN_NB, SCAN_BS, 0, stream>>>(hist, bsum, N);
    scan2_kernel<<<1, SCAN_BS, 0, stream>>>(bsum, bpre, SCAN_NB, row_ptr, N);
    scan3_kernel<<<SCAN_NB, SCAN_BS, 0, stream>>>(hist, bpre, row_ptr, cursor, N);
    fill_kernel<<<(E + 255) / 256, 256, 0, stream>>>(esrc, edst, E, cursor, edge_data, dinv);

    // ---- prep: x -> bf16; pack transposed bf16 weights ----
    cvt_bf16_kernel<<<(N * 128 / 4 + 255) / 256, 256, 0, stream>>>(x, (uint2*)xb, N * 128 / 4);
    pack_wcat_kernel<<<(384 * 128 + 255) / 256, 256, 0, stream>>>(W_s1, W_m21, W_m1,
                                                                  b_s1, b_m21, b_m1, Wcat_t, bcat);
    tpack_kernel<<<(128 * 128 + 255) / 256, 256, 0, stream>>>(W_s2, Ws2_t, 128, 128);
    tpack_kernel<<<(128 * 128 + 255) / 256, 256, 0, stream>>>(W_m22, Wm22_t, 128, 128);
    tpack_kernel<<<(256 * 64 + 255) / 256, 256, 0, stream>>>(W_fc, Wfc_t, 256, 64);

    // ---- layer 1: one bf16 aggregation feeds one fused MFMA GEMM ----
    agg_bf16<128><<<(N + 3) / 4, 256, 0, stream>>>(xb, 128, agg_x, 128, row_ptr, edge_data, dinv, N);

    dim3 gm384((N + 127) / 128, 3);
    dim3 gm128((N + 127) / 128, 1);
    // cat1 = relu(agg_x @ [W_s1|W_m21|W_m1] + bcat), bf16 out
    mfma_gemm_kernel<<<gm384, 256, 0, stream>>>(agg_x, 128, Wcat_t, bcat, cat1, 384, N, 1, 1);

    // ---- layer 2: one 256-channel bf16 aggregation of [h_s1 | h2a] ----
    agg_bf16<256><<<(N + 3) / 4, 256, 0, stream>>>(cat1, 384, bufB, 256, row_ptr, edge_data, dinv, N);

    // h_struct -> comb[:, 0:128] (bf16)
    mfma_gemm_kernel<<<gm128, 256, 0, stream>>>(bufB, 256, Ws2_t, b_s2, comb, 256, N, 1, 1);
    // h2 -> h2buf (bf16)
    mfma_gemm_kernel<<<gm128, 256, 0, stream>>>(bufB + 128, 256, Wm22_t, b_m22, h2buf, 128, N, 1, 1);

    // ---- attention fusion: h_meta -> comb[:, 128:256] (bf16) ----
    attn_kernel<<<N, 64, 0, stream>>>(cat1, h2buf, W_att, b_att, comb + 128, 256);

    // ---- final: out = comb @ W_fc + b_fc (bf16 MFMA, fp32 out) ----
    mfma_fc_kernel<<<(N + 63) / 64, 256, 0, stream>>>(comb, Wfc_t, b_fc, out, N);
}

// Round 7
// 383.574 us; speedup vs baseline: 1.9604x; 1.0794x over previous
//
#include <hip/hip_runtime.h>
#include <hip/hip_bf16.h>

#define N_NODES 50000
#define N_EDGES 800000
#define IN_C 128
#define HID_C 128
#define OUT_C 64

#define SCAN_BS 256
#define SCAN_NB ((N_NODES + SCAN_BS - 1) / SCAN_BS)   // 196

// prep kernel block-range layout
#define PREP_CVT_NB   6250   // N*128/4 / 256
#define PREP_DEG_NB   3125   // E / 256
#define PREP_WCAT_NB  192    // 384*128 / 256
#define PREP_TP_NB    64     // 128*128 / 256 (and 64*256/256)
#define PREP_NB (PREP_CVT_NB + PREP_DEG_NB + PREP_WCAT_NB + 3 * PREP_TP_NB)

typedef __attribute__((ext_vector_type(8))) short bf16x8;
typedef __attribute__((ext_vector_type(4))) float f32x4;

__device__ __forceinline__ ushort f2bf(float f) {
    unsigned u = __float_as_uint(f);
    return (ushort)((u + 0x7fffu + ((u >> 16) & 1u)) >> 16);
}
__device__ __forceinline__ float bf2f(ushort u) {
    return __uint_as_float(((unsigned)u) << 16);
}

// ---------------------------------------------------------------------------
// Fused prep: x->bf16 cvt | degree histogram | weight packs | row_ptr[N]=E
// Independent work items partitioned by blockIdx.x range (1 dispatch).
// ---------------------------------------------------------------------------
__global__ __launch_bounds__(256)
void prep_kernel(const float* __restrict__ x, uint2* __restrict__ xb4,
                 const int* __restrict__ edst, int* __restrict__ hist,
                 const float* __restrict__ Ws1, const float* __restrict__ Wm21,
                 const float* __restrict__ Wm1,
                 const float* __restrict__ bs1, const float* __restrict__ bm21,
                 const float* __restrict__ bm1,
                 ushort* __restrict__ Wcat_t, float* __restrict__ bcat,
                 const float* __restrict__ Ws2, ushort* __restrict__ Ws2t,
                 const float* __restrict__ Wm22, ushort* __restrict__ Wm22t,
                 const float* __restrict__ Wfc, ushort* __restrict__ Wfct,
                 int* __restrict__ row_ptr) {
    const int bid = blockIdx.x;
    const int t = threadIdx.x;
    if (bid < PREP_CVT_NB) {
        int i = bid * 256 + t;                     // exactly N*128/4
        float4 v = *(const float4*)&x[(size_t)i * 4];
        uint2 o;
        o.x = (uint)f2bf(v.x) | ((uint)f2bf(v.y) << 16);
        o.y = (uint)f2bf(v.z) | ((uint)f2bf(v.w) << 16);
        xb4[i] = o;
    } else if (bid < PREP_CVT_NB + PREP_DEG_NB) {
        int e = (bid - PREP_CVT_NB) * 256 + t;     // exactly E
        atomicAdd(&hist[edst[e]], 1);
    } else if (bid < PREP_CVT_NB + PREP_DEG_NB + PREP_WCAT_NB) {
        int idx = (bid - PREP_CVT_NB - PREP_DEG_NB) * 256 + t;  // < 49152
        int c = idx >> 7, k = idx & 127;
        float v = (c < 128) ? Ws1[k * 128 + c]
                : (c < 256) ? Wm21[k * 128 + (c - 128)]
                            : Wm1[k * 128 + (c - 256)];
        Wcat_t[idx] = f2bf(v);
        if (idx < 384) {
            bcat[idx] = (idx < 128) ? bs1[idx] : (idx < 256) ? bm21[idx - 128] : bm1[idx - 256];
        }
        if (idx == 0) row_ptr[N_NODES] = N_EDGES;
    } else if (bid < PREP_CVT_NB + PREP_DEG_NB + PREP_WCAT_NB + PREP_TP_NB) {
        int idx = (bid - PREP_CVT_NB - PREP_DEG_NB - PREP_WCAT_NB) * 256 + t;  // < 16384
        int c = idx >> 7, k = idx & 127;
        Ws2t[idx] = f2bf(Ws2[(size_t)k * 128 + c]);
    } else if (bid < PREP_CVT_NB + PREP_DEG_NB + PREP_WCAT_NB + 2 * PREP_TP_NB) {
        int idx = (bid - PREP_CVT_NB - PREP_DEG_NB - PREP_WCAT_NB - PREP_TP_NB) * 256 + t;
        int c = idx >> 7, k = idx & 127;
        Wm22t[idx] = f2bf(Wm22[(size_t)k * 128 + c]);
    } else {
        int idx = (bid - PREP_CVT_NB - PREP_DEG_NB - PREP_WCAT_NB - 2 * PREP_TP_NB) * 256 + t;
        int c = idx >> 8, k = idx & 255;           // Wfc [256][64] -> Wfct [64][256]
        Wfct[idx] = f2bf(Wfc[(size_t)k * 64 + c]);
    }
}

// ---------------------------------------------------------------------------
// scan phase 1: per-block sums of hist + dinv = rsqrt(deg+1)
// ---------------------------------------------------------------------------
__global__ __launch_bounds__(SCAN_BS)
void scan1_kernel(const int* __restrict__ hist, int* __restrict__ bsum,
                  float* __restrict__ dinv, int n) {
    __shared__ int s[SCAN_BS];
    int t = threadIdx.x;
    int i = blockIdx.x * SCAN_BS + t;
    int v = (i < n) ? hist[i] : 0;
    if (i < n) dinv[i] = rsqrtf((float)(v + 1));
    s[t] = v;
    __syncthreads();
#pragma unroll
    for (int off = SCAN_BS / 2; off > 0; off >>= 1) {
        if (t < off) s[t] += s[t + off];
        __syncthreads();
    }
    if (t == 0) bsum[blockIdx.x] = s[0];
}

// ---------------------------------------------------------------------------
// scan phase 2 (final): each block computes its own bsum-prefix (<=196 ints),
// then local exclusive scan -> row_ptr & cursor
// ---------------------------------------------------------------------------
__global__ __launch_bounds__(SCAN_BS)
void scan3_kernel(const int* __restrict__ hist, const int* __restrict__ bsum,
                  int* __restrict__ row_ptr, int* __restrict__ cursor, int n) {
    __shared__ int s[SCAN_BS];
    __shared__ int pre_s;
    int t = threadIdx.x;
    int b = blockIdx.x;
    int p = 0;
    for (int j = t; j < b; j += SCAN_BS) p += bsum[j];
    s[t] = p;
    __syncthreads();
#pragma unroll
    for (int off = SCAN_BS / 2; off > 0; off >>= 1) {
        if (t < off) s[t] += s[t + off];
        __syncthreads();
    }
    if (t == 0) pre_s = s[0];
    __syncthreads();
    const int pre = pre_s;
    __syncthreads();
    int i = b * SCAN_BS + t;
    int v = (i < n) ? hist[i] : 0;
    s[t] = v;
    __syncthreads();
#pragma unroll
    for (int off = 1; off < SCAN_BS; off <<= 1) {
        int tmp = (t >= off) ? s[t - off] : 0;
        __syncthreads();
        s[t] += tmp;
        __syncthreads();
    }
    if (i < n) {
        int ex = s[t] - v + pre;
        row_ptr[i] = ex;
        cursor[i]  = ex;
    }
}

__global__ void fill_kernel(const int* __restrict__ src, const int* __restrict__ dst, int E,
                            int* __restrict__ cursor, int2* __restrict__ edge_data,
                            const float* __restrict__ dinv) {
    int e = blockIdx.x * blockDim.x + threadIdx.x;
    if (e < E) {
        int d = dst[e];
        int s = src[e];
        int pos = atomicAdd(&cursor[d], 1);
        edge_data[pos] = make_int2(s, __float_as_int(dinv[s]));
    }
}

// ---------------------------------------------------------------------------
// bf16-gather aggregation, bf16 OUT. One wave per node, 4x unrolled edge loop.
// ---------------------------------------------------------------------------
template<int C>
__global__ __launch_bounds__(256)
void agg_bf16(const ushort* __restrict__ X, int ldx,
              ushort* __restrict__ Y, int ldy,
              const int* __restrict__ row_ptr,
              const int2* __restrict__ edge_data,
              const float* __restrict__ dinv, int n) {
    constexpr int CG = C / 8;       // lanes per row
    constexpr int SLOTS = 64 / CG;  // 2 for C=256, 4 for C=128
    const int wid = blockIdx.x * (blockDim.x >> 6) + (threadIdx.x >> 6);
    if (wid >= n) return;
    const int lane = threadIdx.x & 63;
    const int cg = lane & (CG - 1);
    const int slot = lane / CG;

    const float di = dinv[wid];
    float acc[8] = {0.f, 0.f, 0.f, 0.f, 0.f, 0.f, 0.f, 0.f};

    auto fma_row = [&](uint4 v, float w) {
        acc[0] = fmaf(w, __uint_as_float(v.x << 16), acc[0]);
        acc[1] = fmaf(w, __uint_as_float(v.x & 0xffff0000u), acc[1]);
        acc[2] = fmaf(w, __uint_as_float(v.y << 16), acc[2]);
        acc[3] = fmaf(w, __uint_as_float(v.y & 0xffff0000u), acc[3]);
        acc[4] = fmaf(w, __uint_as_float(v.z << 16), acc[4]);
        acc[5] = fmaf(w, __uint_as_float(v.z & 0xffff0000u), acc[5]);
        acc[6] = fmaf(w, __uint_as_float(v.w << 16), acc[6]);
        acc[7] = fmaf(w, __uint_as_float(v.w & 0xffff0000u), acc[7]);
    };

    if (slot == 0) {
        uint4 v = *(const uint4*)&X[(size_t)wid * ldx + cg * 8];
        fma_row(v, di * di);
    }
    const int e0 = row_ptr[wid], e1 = row_ptr[wid + 1];
    int e = e0 + slot;
    for (; e + 3 * SLOTS < e1; e += 4 * SLOTS) {
        const int2 d0 = edge_data[e];
        const int2 d1 = edge_data[e + SLOTS];
        const int2 d2 = edge_data[e + 2 * SLOTS];
        const int2 d3 = edge_data[e + 3 * SLOTS];
        const uint4 v0 = *(const uint4*)&X[(size_t)d0.x * ldx + cg * 8];
        const uint4 v1 = *(const uint4*)&X[(size_t)d1.x * ldx + cg * 8];
        const uint4 v2 = *(const uint4*)&X[(size_t)d2.x * ldx + cg * 8];
        const uint4 v3 = *(const uint4*)&X[(size_t)d3.x * ldx + cg * 8];
        fma_row(v0, di * __int_as_float(d0.y));
        fma_row(v1, di * __int_as_float(d1.y));
        fma_row(v2, di * __int_as_float(d2.y));
        fma_row(v3, di * __int_as_float(d3.y));
    }
    for (; e < e1; e += SLOTS) {
        const int2 d0 = edge_data[e];
        const uint4 v0 = *(const uint4*)&X[(size_t)d0.x * ldx + cg * 8];
        fma_row(v0, di * __int_as_float(d0.y));
    }
#pragma unroll
    for (int j = 0; j < 8; ++j) {
        if (SLOTS == 4) acc[j] += __shfl_xor(acc[j], 16);
        if (SLOTS >= 2) acc[j] += __shfl_xor(acc[j], 32);
    }
    if (slot == 0) {
        uint4 o;
        o.x = (uint)f2bf(acc[0]) | ((uint)f2bf(acc[1]) << 16);
        o.y = (uint)f2bf(acc[2]) | ((uint)f2bf(acc[3]) << 16);
        o.z = (uint)f2bf(acc[4]) | ((uint)f2bf(acc[5]) << 16);
        o.w = (uint)f2bf(acc[6]) | ((uint)f2bf(acc[7]) << 16);
        *(uint4*)&Y[(size_t)wid * ldy + cg * 8] = o;
    }
}

// ---------------------------------------------------------------------------
// bf16 MFMA GEMM, K=128 fixed. BM=128, BN=128, 256 threads (4 waves).
// Used for the fused layer-1 GEMM (3 column blocks).
// ---------------------------------------------------------------------------
__global__ __launch_bounds__(256)
void mfma_gemm_kernel(const ushort* __restrict__ A, int lda,
                      const ushort* __restrict__ Wt,  // [C][128] bf16
                      const float* __restrict__ bias,
                      void* __restrict__ Yv, int ldy,
                      int M, int relu, int obf16) {
    __shared__ char Asmem[128 * 272];   // 128 rows x (256B data + 16B pad)
    const int tid = threadIdx.x;
    const int lane = tid & 63;
    const int w = tid >> 6;
    const int rb = blockIdx.x * 128;
    const int cb = blockIdx.y * 128;

    {
        const int rowbase = tid >> 4;
        const int inrow = (tid & 15) * 8;
#pragma unroll
        for (int it = 0; it < 8; ++it) {
            int row = it * 16 + rowbase;
            uint4 v = make_uint4(0u, 0u, 0u, 0u);
            int r = rb + row;
            if (r < M) v = *(const uint4*)&A[(size_t)r * lda + inrow];
            *(uint4*)&Asmem[row * 272 + (tid & 15) * 16] = v;
        }
    }
    __syncthreads();

    f32x4 acc[2][8];
#pragma unroll
    for (int i = 0; i < 2; ++i)
#pragma unroll
        for (int j = 0; j < 8; ++j) acc[i][j] = (f32x4){0.f, 0.f, 0.f, 0.f};

    const int arow0 = w * 32 + (lane & 15);
    const int kq = (lane >> 4) * 8;
    const int ccol = lane & 15;
#pragma unroll
    for (int ks = 0; ks < 4; ++ks) {
        const int k0 = ks * 32;
        const bf16x8 a0 = *(const bf16x8*)&Asmem[arow0 * 272 + (k0 + kq) * 2];
        const bf16x8 a1 = *(const bf16x8*)&Asmem[(arow0 + 16) * 272 + (k0 + kq) * 2];
#pragma unroll
        for (int ct = 0; ct < 8; ++ct) {
            const bf16x8 b = *(const bf16x8*)&Wt[(size_t)(cb + ct * 16 + ccol) * 128 + k0 + kq];
            acc[0][ct] = __builtin_amdgcn_mfma_f32_16x16x32_bf16(a0, b, acc[0][ct], 0, 0, 0);
            acc[1][ct] = __builtin_amdgcn_mfma_f32_16x16x32_bf16(a1, b, acc[1][ct], 0, 0, 0);
        }
    }

    const int rowq = (lane >> 4) * 4;
#pragma unroll
    for (int rt = 0; rt < 2; ++rt) {
#pragma unroll
        for (int ct = 0; ct < 8; ++ct) {
            const int col = cb + ct * 16 + ccol;
            const float bcol = bias[col];
#pragma unroll
            for (int r = 0; r < 4; ++r) {
                const int row = rb + w * 32 + rt * 16 + rowq + r;
                if (row >= M) continue;
                float v = acc[rt][ct][r] + bcol;
                if (relu) v = fmaxf(v, 0.f);
                if (obf16) ((ushort*)Yv)[(size_t)row * ldy + col] = f2bf(v);
                else       ((float*)Yv)[(size_t)row * ldy + col] = v;
            }
        }
    }
}

// ---------------------------------------------------------------------------
// Layer-2 fused GEMM: blockIdx.y==0 -> h_struct = relu(bufB[:,0:128] @ W_s2)
// into comb[:,0:128]. blockIdx.y==1 -> h2 = relu(bufB[:,128:256] @ W_m22)
// kept in registers, attention vs h1 (cat1[:,256:384]) computed in-epilogue
// (quad-group shfl reductions), h_meta written to comb[:,128:256].
// ---------------------------------------------------------------------------
__global__ __launch_bounds__(256)
void gemm2_kernel(const ushort* __restrict__ bufB,
                  const ushort* __restrict__ Ws2t, const float* __restrict__ bs2,
                  const ushort* __restrict__ Wm22t, const float* __restrict__ bm22,
                  const ushort* __restrict__ cat1,
                  const float* __restrict__ Watt, const float* __restrict__ batt,
                  ushort* __restrict__ comb, int M) {
    __shared__ char Asmem[128 * 272];
    const int tid = threadIdx.x;
    const int lane = tid & 63;
    const int w = tid >> 6;
    const int rb = blockIdx.x * 128;
    const int branch = blockIdx.y;
    const ushort* A = bufB + (branch ? 128 : 0);
    const ushort* Wt = branch ? Wm22t : Ws2t;
    const float* bias = branch ? bm22 : bs2;

    {
        const int rowbase = tid >> 4;
        const int seg = tid & 15;
#pragma unroll
        for (int it = 0; it < 8; ++it) {
            int row = it * 16 + rowbase;
            uint4 v = make_uint4(0u, 0u, 0u, 0u);
            int r = rb + row;
            if (r < M) v = *(const uint4*)&A[(size_t)r * 256 + seg * 8];
            *(uint4*)&Asmem[row * 272 + seg * 16] = v;
        }
    }
    __syncthreads();

    f32x4 acc[2][8];
#pragma unroll
    for (int i = 0; i < 2; ++i)
#pragma unroll
        for (int j = 0; j < 8; ++j) acc[i][j] = (f32x4){0.f, 0.f, 0.f, 0.f};

    const int arow0 = w * 32 + (lane & 15);
    const int kq = (lane >> 4) * 8;
    const int ccol = lane & 15;
#pragma unroll
    for (int ks = 0; ks < 4; ++ks) {
        const int k0 = ks * 32;
        const bf16x8 a0 = *(const bf16x8*)&Asmem[arow0 * 272 + (k0 + kq) * 2];
        const bf16x8 a1 = *(const bf16x8*)&Asmem[(arow0 + 16) * 272 + (k0 + kq) * 2];
#pragma unroll
        for (int ct = 0; ct < 8; ++ct) {
            const bf16x8 b = *(const bf16x8*)&Wt[(size_t)(ct * 16 + ccol) * 128 + k0 + kq];
            acc[0][ct] = __builtin_amdgcn_mfma_f32_16x16x32_bf16(a0, b, acc[0][ct], 0, 0, 0);
            acc[1][ct] = __builtin_amdgcn_mfma_f32_16x16x32_bf16(a1, b, acc[1][ct], 0, 0, 0);
        }
    }

    const int quad = lane >> 4;
    if (branch == 0) {
        // h_struct -> comb[:,0:128]
#pragma unroll
        for (int rt = 0; rt < 2; ++rt) {
#pragma unroll
            for (int ct = 0; ct < 8; ++ct) {
                const int col = ct * 16 + ccol;
                const float bcol = bias[col];
#pragma unroll
                for (int r = 0; r < 4; ++r) {
                    const int row = rb + w * 32 + rt * 16 + quad * 4 + r;
                    if (row >= M) continue;
                    comb[(size_t)row * 256 + col] = f2bf(fmaxf(acc[rt][ct][r] + bcol, 0.f));
                }
            }
        }
    } else {
        // h2 in regs: bias + relu in place
#pragma unroll
        for (int rt = 0; rt < 2; ++rt)
#pragma unroll
            for (int ct = 0; ct < 8; ++ct) {
                const float bcol = bias[ct * 16 + ccol];
#pragma unroll
                for (int r = 0; r < 4; ++r)
                    acc[rt][ct][r] = fmaxf(acc[rt][ct][r] + bcol, 0.f);
            }
        float wv[8];
#pragma unroll
        for (int ct = 0; ct < 8; ++ct) wv[ct] = Watt[ct * 16 + ccol];
        const float ba = batt[0];
#pragma unroll
        for (int rt = 0; rt < 2; ++rt) {
#pragma unroll
            for (int r = 0; r < 4; ++r) {
                const int row0 = rb + w * 32 + rt * 16 + quad * 4 + r;
                const int rowc = (row0 < M) ? row0 : (M - 1);   // clamp for safe loads
                const ushort* h1row = &cat1[(size_t)rowc * 384 + 256];
                float bp = 0.f, ap = 0.f;
#pragma unroll
                for (int ct = 0; ct < 8; ++ct) {
                    bp += acc[rt][ct][r] * wv[ct];
                    ap += bf2f(h1row[ct * 16 + ccol]) * wv[ct];
                }
#pragma unroll
                for (int off = 1; off < 16; off <<= 1) {
                    bp += __shfl_xor(bp, off);
                    ap += __shfl_xor(ap, off);
                }
                const float a = ap + ba, b = bp + ba;
                const float m = fmaxf(a, b);
                const float ea = __expf(a - m), eb = __expf(b - m);
                const float inv = 1.f / (ea + eb);
                const float wa = ea * inv, wb = eb * inv;
                if (row0 < M) {
#pragma unroll
                    for (int ct = 0; ct < 8; ++ct) {
                        const float h1 = bf2f(h1row[ct * 16 + ccol]);
                        comb[(size_t)row0 * 256 + 128 + ct * 16 + ccol] =
                            f2bf(fmaf(wa, h1, wb * acc[rt][ct][r]));
                    }
                }
            }
        }
    }
}

// ---------------------------------------------------------------------------
// bf16 MFMA fc GEMM: K=256, N=64. BM=64, 256 threads. fp32 out (d_out).
// ---------------------------------------------------------------------------
__global__ __launch_bounds__(256)
void mfma_fc_kernel(const ushort* __restrict__ A,
                    const ushort* __restrict__ Wt,
                    const float* __restrict__ bias,
                    float* __restrict__ Y, int M) {
    __shared__ char Asmem[64 * 528];
    const int tid = threadIdx.x;
    const int lane = tid & 63;
    const int w = tid >> 6;
    const int rb = blockIdx.x * 64;

    {
        const int rowbase = tid >> 5;
        const int seg = (tid & 31);
#pragma unroll
        for (int it = 0; it < 8; ++it) {
            int row = it * 8 + rowbase;
            uint4 v = make_uint4(0u, 0u, 0u, 0u);
            int r = rb + row;
            if (r < M) v = *(const uint4*)&A[(size_t)r * 256 + seg * 8];
            *(uint4*)&Asmem[row * 528 + seg * 16] = v;
        }
    }
    __syncthreads();

    f32x4 acc[4];
#pragma unroll
    for (int j = 0; j < 4; ++j) acc[j] = (f32x4){0.f, 0.f, 0.f, 0.f};

    const int arow = w * 16 + (lane & 15);
    const int kq = (lane >> 4) * 8;
    const int ccol = lane & 15;
#pragma unroll
    for (int ks = 0; ks < 8; ++ks) {
        const int k0 = ks * 32;
        const bf16x8 a = *(const bf16x8*)&Asmem[arow * 528 + (k0 + kq) * 2];
#pragma unroll
        for (int ct = 0; ct < 4; ++ct) {
            const bf16x8 b = *(const bf16x8*)&Wt[(size_t)(ct * 16 + ccol) * 256 + k0 + kq];
            acc[ct] = __builtin_amdgcn_mfma_f32_16x16x32_bf16(a, b, acc[ct], 0, 0, 0);
        }
    }

    const int rowq = (lane >> 4) * 4;
#pragma unroll
    for (int ct = 0; ct < 4; ++ct) {
        const int col = ct * 16 + ccol;
        const float bcol = bias[col];
#pragma unroll
        for (int r = 0; r < 4; ++r) {
            const int row = rb + w * 16 + rowq + r;
            if (row < M) Y[(size_t)row * 64 + col] = acc[ct][r] + bcol;
        }
    }
}

// ---------------------------------------------------------------------------
extern "C" void kernel_launch(void* const* d_in, const int* in_sizes, int n_in,
                              void* d_out, int out_size, void* d_ws, size_t ws_size,
                              hipStream_t stream) {
    const int N = N_NODES, E = N_EDGES;
    const float* x     = (const float*)d_in[0];
    const int*   ei    = (const int*)d_in[1];
    const int*   esrc  = ei;
    const int*   edst  = ei + E;
    const float* W_s1  = (const float*)d_in[2];
    const float* b_s1  = (const float*)d_in[3];
    const float* W_s2  = (const float*)d_in[4];
    const float* b_s2  = (const float*)d_in[5];
    const float* W_m1  = (const float*)d_in[6];
    const float* b_m1  = (const float*)d_in[7];
    const float* W_m21 = (const float*)d_in[8];
    const float* b_m21 = (const float*)d_in[9];
    const float* W_m22 = (const float*)d_in[10];
    const float* b_m22 = (const float*)d_in[11];
    const float* W_att = (const float*)d_in[12];
    const float* b_att = (const float*)d_in[13];
    const float* W_fc  = (const float*)d_in[14];
    const float* b_fc  = (const float*)d_in[15];
    float* out = (float*)d_out;

    char* base = (char*)d_ws;
    size_t off = 0;
    auto take = [&](size_t nbytes) -> void* {
        void* p = base + off;
        off += (nbytes + 255) & ~(size_t)255;
        return p;
    };
    int*    hist      = (int*)take((size_t)N * 4);
    int*    cursor    = (int*)take((size_t)N * 4);
    int*    row_ptr   = (int*)take((size_t)(N + 1) * 4);
    int*    bsum      = (int*)take((size_t)SCAN_NB * 4);
    int2*   edge_data = (int2*)take((size_t)E * 8);
    float*  dinv      = (float*)take((size_t)N * 4);
    ushort* xb        = (ushort*)take((size_t)N * 128 * 2);   // x bf16
    ushort* agg_x     = (ushort*)take((size_t)N * 128 * 2);   // S @ x, bf16
    ushort* cat1      = (ushort*)take((size_t)N * 384 * 2);   // [h_s1 | h2a | h1] bf16
    ushort* bufB      = (ushort*)take((size_t)N * 256 * 2);   // S @ cat1[:,0:256], bf16
    ushort* comb      = (ushort*)take((size_t)N * 256 * 2);   // [h_struct | h_meta] bf16
    ushort* Wcat_t    = (ushort*)take((size_t)384 * 128 * 2); // [c][k] bf16
    ushort* Ws2_t     = (ushort*)take((size_t)128 * 128 * 2);
    ushort* Wm22_t    = (ushort*)take((size_t)128 * 128 * 2);
    ushort* Wfc_t     = (ushort*)take((size_t)64 * 256 * 2);
    float*  bcat      = (float*)take((size_t)384 * 4);

    // 1. zero hist
    hipMemsetAsync(hist, 0, (size_t)N * 4, stream);
    // 2. fused prep: cvt + degree + packs + row_ptr[N]
    prep_kernel<<<PREP_NB, 256, 0, stream>>>(x, (uint2*)xb, edst, hist,
                                             W_s1, W_m21, W_m1, b_s1, b_m21, b_m1,
                                             Wcat_t, bcat, W_s2, Ws2_t, W_m22, Wm22_t,
                                             W_fc, Wfc_t, row_ptr);
    // 3-4. scan (2 phases) -> row_ptr/cursor (+dinv in phase 1)
    scan1_kernel<<<SCAN_NB, SCAN_BS, 0, stream>>>(hist, bsum, dinv, N);
    scan3_kernel<<<SCAN_NB, SCAN_BS, 0, stream>>>(hist, bsum, row_ptr, cursor, N);
    // 5. fill CSR edges with (src, dinv[src])
    fill_kernel<<<(E + 255) / 256, 256, 0, stream>>>(esrc, edst, E, cursor, edge_data, dinv);

    // 6. layer-1 aggregation
    agg_bf16<128><<<(N + 3) / 4, 256, 0, stream>>>(xb, 128, agg_x, 128, row_ptr, edge_data, dinv, N);
    // 7. fused layer-1 GEMM: cat1 = relu(agg_x @ [W_s1|W_m21|W_m1] + bcat)
    dim3 gm384((N + 127) / 128, 3);
    mfma_gemm_kernel<<<gm384, 256, 0, stream>>>(agg_x, 128, Wcat_t, bcat, cat1, 384, N, 1, 1);
    // 8. layer-2 aggregation of [h_s1 | h2a]
    agg_bf16<256><<<(N + 3) / 4, 256, 0, stream>>>(cat1, 384, bufB, 256, row_ptr, edge_data, dinv, N);
    // 9. fused layer-2 GEMMs + attention -> comb
    dim3 gm2((N + 127) / 128, 2);
    gemm2_kernel<<<gm2, 256, 0, stream>>>(bufB, Ws2_t, b_s2, Wm22_t, b_m22,
                                          cat1, W_att, b_att, comb, N);
    // 10. final fc
    mfma_fc_kernel<<<(N + 63) / 64, 256, 0, stream>>>(comb, Wfc_t, b_fc, out, N);
}